// Round 1
// baseline (1461.418 us; speedup 1.0000x reference)
//
#include <hip/hip_runtime.h>
#include <math.h>

#define NEG_SLOPE 0.2f

__device__ __forceinline__ float lrelu(float x) { return x > 0.f ? x : NEG_SLOPE * x; }

__device__ __forceinline__ float sel4(const float4 v, int h) {
  float r = v.x;
  r = (h == 1) ? v.y : r;
  r = (h == 2) ? v.z : r;
  r = (h == 3) ? v.w : r;
  return r;
}

// ---------------- CSR build ----------------

__global__ void k_hist(const int* __restrict__ dst, int* __restrict__ cnt, int E) {
  int i = blockIdx.x * blockDim.x + threadIdx.x;
  if (i < E) atomicAdd(&cnt[dst[i]], 1);
}

__global__ __launch_bounds__(256) void k_offsets(const int* __restrict__ cnt,
                                                 int* __restrict__ row_start,
                                                 int* __restrict__ gcount, int N) {
  __shared__ int s[256];
  __shared__ int base;
  int tid = threadIdx.x;
  int i = blockIdx.x * 256 + tid;
  int c = (i < N) ? cnt[i] : 0;
  s[tid] = c;
  __syncthreads();
  // inclusive Hillis-Steele scan
  for (int off = 1; off < 256; off <<= 1) {
    int v = 0;
    if (tid >= off) v = s[tid - off];
    __syncthreads();
    if (tid >= off) s[tid] += v;
    __syncthreads();
  }
  if (tid == 255) base = atomicAdd(gcount, s[255]);
  __syncthreads();
  if (i < N) row_start[i] = base + s[tid] - c;  // exclusive within block + block base
}

__global__ void k_scatter(const int* __restrict__ src, const int* __restrict__ dst,
                          const int* __restrict__ row_start, int* __restrict__ fill,
                          int* __restrict__ srcs, int E) {
  int i = blockIdx.x * blockDim.x + threadIdx.x;
  if (i < E) {
    int d = dst[i];
    int p = row_start[d] + atomicAdd(&fill[d], 1);
    srcs[p] = src[i];
  }
}

// ---------------- attention weight folding ----------------
// wlr[k][h]   = sum_d Ws[k, h*Dh+d] * al[h,d]
// wlr[k][4+h] = sum_d Wd[k, h*Dh+d] * ar[h,d]
__global__ void k_wlr(const float* __restrict__ Ws, const float* __restrict__ Wd,
                      const float* __restrict__ al, const float* __restrict__ ar,
                      float* __restrict__ wlr, int K, int Dh) {
  int i = blockIdx.x * blockDim.x + threadIdx.x;
  int M = 4 * Dh;
  if (i < K * 4) {
    int k = i >> 2, h = i & 3;
    float sl = 0.f, sr = 0.f;
    for (int d = 0; d < Dh; d++) {
      sl += Ws[(size_t)k * M + h * Dh + d] * al[h * Dh + d];
      sr += Wd[(size_t)k * M + h * Dh + d] * ar[h * Dh + d];
    }
    wlr[k * 8 + h] = sl;
    wlr[k * 8 + 4 + h] = sr;
  }
}

__global__ void k_padw(const float* __restrict__ W, float* __restrict__ Wp, int K) {
  int i = blockIdx.x * blockDim.x + threadIdx.x;  // over K*192
  if (i < K * 192) {
    int k = i / 192, c = i % 192;
    Wp[i] = (c < 188) ? W[(size_t)k * 188 + c] : 0.f;
  }
}

// ---------------- el/er: h @ wlr  ([N,K] x [K,8]) ----------------
__global__ __launch_bounds__(256) void k_eler(const float* __restrict__ H,
                                              const float* __restrict__ wlr,
                                              float* __restrict__ el, float* __restrict__ er,
                                              int N, int K) {
  __shared__ float ws[2048];  // K*8 <= 2048
  for (int i = threadIdx.x; i < K * 8; i += 256) ws[i] = wlr[i];
  __syncthreads();
  int lane = threadIdx.x & 63;
  int node = blockIdx.x * 4 + (threadIdx.x >> 6);
  if (node >= N) return;
  float p[8] = {0, 0, 0, 0, 0, 0, 0, 0};
  for (int k = lane; k < K; k += 64) {
    float hv = H[(size_t)node * K + k];
#pragma unroll
    for (int j = 0; j < 8; j++) p[j] += hv * ws[k * 8 + j];
  }
#pragma unroll
  for (int j = 0; j < 8; j++) {
#pragma unroll
    for (int m = 1; m < 64; m <<= 1) p[j] += __shfl_xor(p[j], m);
  }
  if (lane == 0) {
    *(float4*)&el[(size_t)node * 4] = make_float4(p[0], p[1], p[2], p[3]);
    *(float4*)&er[(size_t)node * 4] = make_float4(p[4], p[5], p[6], p[7]);
  }
}

// ---------------- fp32 GEMM: C[N,BN] = A[N,K] @ B[K,BN] ----------------
template <int BN, int TN>
__global__ __launch_bounds__(256) void k_gemm(const float* __restrict__ A,
                                              const float* __restrict__ B,
                                              float* __restrict__ C, int N, int K) {
  __shared__ float As[32][68];  // [k][row], padded stride 68 (16B-aligned rows, low conflicts)
  __shared__ float Bs[32][BN];
  const int tid = threadIdx.x;
  const int tx = tid & 15, ty = tid >> 4;
  const int row0 = blockIdx.x * 64;
  float acc[4][TN];
#pragma unroll
  for (int i = 0; i < 4; i++)
#pragma unroll
    for (int j = 0; j < TN; j++) acc[i][j] = 0.f;

  for (int k0 = 0; k0 < K; k0 += 32) {
#pragma unroll
    for (int i = 0; i < 2; i++) {
      int idx = tid + i * 256;       // [0,512)
      int r = idx >> 3, kq = idx & 7;
      int grow = row0 + r;
      float4 v = make_float4(0.f, 0.f, 0.f, 0.f);
      if (grow < N) v = *(const float4*)&A[(size_t)grow * K + k0 + kq * 4];
      As[kq * 4 + 0][r] = v.x;
      As[kq * 4 + 1][r] = v.y;
      As[kq * 4 + 2][r] = v.z;
      As[kq * 4 + 3][r] = v.w;
    }
#pragma unroll
    for (int i = 0; i < BN / 32; i++) {
      int idx = tid + i * 256;
      int kr = idx / (BN / 4), c4 = idx % (BN / 4);
      *(float4*)&Bs[kr][c4 * 4] = *(const float4*)&B[(size_t)(k0 + kr) * BN + c4 * 4];
    }
    __syncthreads();
#pragma unroll
    for (int kk = 0; kk < 32; kk++) {
      float4 a = *(const float4*)&As[kk][ty * 4];
      float av[4] = {a.x, a.y, a.z, a.w};
      float bv[TN];
#pragma unroll
      for (int j = 0; j < TN / 4; j++) *(float4*)&bv[j * 4] = *(const float4*)&Bs[kk][tx * TN + j * 4];
#pragma unroll
      for (int i = 0; i < 4; i++)
#pragma unroll
        for (int j = 0; j < TN; j++) acc[i][j] += av[i] * bv[j];
    }
    __syncthreads();
  }
#pragma unroll
  for (int i = 0; i < 4; i++) {
    int grow = row0 + ty * 4 + i;
    if (grow < N) {
#pragma unroll
      for (int j = 0; j < TN / 4; j++) {
        float4 o = make_float4(acc[i][j * 4], acc[i][j * 4 + 1], acc[i][j * 4 + 2], acc[i][j * 4 + 3]);
        *(float4*)&C[(size_t)grow * BN + tx * TN + j * 4] = o;
      }
    }
  }
}

// ---------------- edge aggregation, layers 0/1 (M=128, relu epilogue) ----------------
__global__ __launch_bounds__(256) void k_edge_mid(
    const float* __restrict__ fs, const float* __restrict__ el, const float* __restrict__ er,
    const int* __restrict__ row_start, const int* __restrict__ cnt, const int* __restrict__ srcs,
    const float* __restrict__ bias, float* __restrict__ hout, int N) {
  int lane = threadIdx.x & 63;
  int v = blockIdx.x * 4 + (threadIdx.x >> 6);
  if (v >= N) return;
  int start = row_start[v], deg = cnt[v];
  float4 erv = *(const float4*)&er[(size_t)v * 4];

  // pass 1: lane-parallel max of leaky(el[u]+er[v]) per head
  float4 m = make_float4(-INFINITY, -INFINITY, -INFINITY, -INFINITY);
  for (int j = lane; j < deg; j += 64) {
    int u = srcs[start + j];
    float4 e = *(const float4*)&el[(size_t)u * 4];
    e.x = lrelu(e.x + erv.x); e.y = lrelu(e.y + erv.y);
    e.z = lrelu(e.z + erv.z); e.w = lrelu(e.w + erv.w);
    m.x = fmaxf(m.x, e.x); m.y = fmaxf(m.y, e.y);
    m.z = fmaxf(m.z, e.z); m.w = fmaxf(m.w, e.w);
  }
#pragma unroll
  for (int msk = 1; msk < 64; msk <<= 1) {
    m.x = fmaxf(m.x, __shfl_xor(m.x, msk));
    m.y = fmaxf(m.y, __shfl_xor(m.y, msk));
    m.z = fmaxf(m.z, __shfl_xor(m.z, msk));
    m.w = fmaxf(m.w, __shfl_xor(m.w, msk));
  }

  // pass 2: lane owns features f0=2*lane, f0+1 (both head h = lane>>4)
  int h = lane >> 4;
  float mh = sel4(m, h);
  float2 acc = make_float2(0.f, 0.f);
  float lh = 0.f;
  for (int j = 0; j < deg; j++) {
    int u = srcs[start + j];  // wave-uniform
    float4 e4 = *(const float4*)&el[(size_t)u * 4];
    float eh = lrelu(sel4(e4, h) + sel4(erv, h));
    float ez = __expf(eh - mh);
    lh += ez;
    float2 f = *(const float2*)&fs[(size_t)u * 128 + 2 * lane];
    acc.x += ez * f.x;
    acc.y += ez * f.y;
  }
  float2 bv = *(const float2*)&bias[2 * lane];
  float2 r;
  if (deg > 0) {
    float inv = 1.f / lh;
    r.x = acc.x * inv + bv.x;
    r.y = acc.y * inv + bv.y;
  } else {
    r = bv;
  }
  r.x = fmaxf(r.x, 0.f);
  r.y = fmaxf(r.y, 0.f);
  *(float2*)&hout[(size_t)v * 128 + 2 * lane] = r;
}

// ---------------- edge aggregation, layer 2 (M=188, stride 192) + head-mean + log_softmax ----------------
__global__ __launch_bounds__(256) void k_edge_final(
    const float* __restrict__ fs, const float* __restrict__ el, const float* __restrict__ er,
    const int* __restrict__ row_start, const int* __restrict__ cnt, const int* __restrict__ srcs,
    const float* __restrict__ b2, float* __restrict__ out, int N) {
  __shared__ float red[4][188];
  int lane = threadIdx.x & 63;
  int w = threadIdx.x >> 6;
  int v = blockIdx.x * 4 + w;
  if (v >= N) return;
  int start = row_start[v], deg = cnt[v];
  float4 erv = *(const float4*)&er[(size_t)v * 4];

  float4 m = make_float4(-INFINITY, -INFINITY, -INFINITY, -INFINITY);
  for (int j = lane; j < deg; j += 64) {
    int u = srcs[start + j];
    float4 e = *(const float4*)&el[(size_t)u * 4];
    e.x = lrelu(e.x + erv.x); e.y = lrelu(e.y + erv.y);
    e.z = lrelu(e.z + erv.z); e.w = lrelu(e.w + erv.w);
    m.x = fmaxf(m.x, e.x); m.y = fmaxf(m.y, e.y);
    m.z = fmaxf(m.z, e.z); m.w = fmaxf(m.w, e.w);
  }
#pragma unroll
  for (int msk = 1; msk < 64; msk <<= 1) {
    m.x = fmaxf(m.x, __shfl_xor(m.x, msk));
    m.y = fmaxf(m.y, __shfl_xor(m.y, msk));
    m.z = fmaxf(m.z, __shfl_xor(m.z, msk));
    m.w = fmaxf(m.w, __shfl_xor(m.w, msk));
  }

  int f0 = 2 * lane;        // [0,128)
  int f2 = 128 + 2 * lane;  // [128,188) valid for lane<30
  int ha = f0 / 47, hb = (f0 + 1) / 47;
  int hc = f2 / 47, hd = (f2 + 1) / 47;  // garbage for lane>=30, unused
  float2 accA = make_float2(0.f, 0.f), accB = make_float2(0.f, 0.f);
  float4 lsum = make_float4(0.f, 0.f, 0.f, 0.f);
  for (int j = 0; j < deg; j++) {
    int u = srcs[start + j];
    float4 e = *(const float4*)&el[(size_t)u * 4];
    e.x = lrelu(e.x + erv.x); e.y = lrelu(e.y + erv.y);
    e.z = lrelu(e.z + erv.z); e.w = lrelu(e.w + erv.w);
    float4 ez;
    ez.x = __expf(e.x - m.x); ez.y = __expf(e.y - m.y);
    ez.z = __expf(e.z - m.z); ez.w = __expf(e.w - m.w);
    lsum.x += ez.x; lsum.y += ez.y; lsum.z += ez.z; lsum.w += ez.w;
    float2 fa = *(const float2*)&fs[(size_t)u * 192 + f0];
    accA.x += sel4(ez, ha) * fa.x;
    accA.y += sel4(ez, hb) * fa.y;
    if (lane < 30) {
      float2 fb = *(const float2*)&fs[(size_t)u * 192 + f2];
      accB.x += sel4(ez, hc) * fb.x;
      accB.y += sel4(ez, hd) * fb.y;
    }
  }
  if (deg > 0) {
    red[w][f0] = accA.x / sel4(lsum, ha) + b2[f0];
    red[w][f0 + 1] = accA.y / sel4(lsum, hb) + b2[f0 + 1];
    if (lane < 30) {
      red[w][f2] = accB.x / sel4(lsum, hc) + b2[f2];
      red[w][f2 + 1] = accB.y / sel4(lsum, hd) + b2[f2 + 1];
    }
  } else {
    red[w][f0] = b2[f0];
    red[w][f0 + 1] = b2[f0 + 1];
    if (lane < 30) {
      red[w][f2] = b2[f2];
      red[w][f2 + 1] = b2[f2 + 1];
    }
  }
  __syncthreads();
  float g = -INFINITY;
  if (lane < 47)
    g = 0.25f * (red[w][lane] + red[w][lane + 47] + red[w][lane + 94] + red[w][lane + 141]);
  float gm = g;
#pragma unroll
  for (int msk = 1; msk < 64; msk <<= 1) gm = fmaxf(gm, __shfl_xor(gm, msk));
  float ex = (lane < 47) ? __expf(g - gm) : 0.f;
  float s = ex;
#pragma unroll
  for (int msk = 1; msk < 64; msk <<= 1) s += __shfl_xor(s, msk);
  if (lane < 47) out[(size_t)v * 47 + lane] = g - gm - __logf(s);
}

// ---------------- launch ----------------
extern "C" void kernel_launch(void* const* d_in, const int* in_sizes, int n_in,
                              void* d_out, int out_size, void* d_ws, size_t ws_size,
                              hipStream_t stream) {
  const float* x = (const float*)d_in[0];
  const int* src = (const int*)d_in[1];
  const int* dst = (const int*)d_in[2];
  const float* W0s = (const float*)d_in[3];
  const float* W0d = (const float*)d_in[4];
  const float* a0l = (const float*)d_in[5];
  const float* a0r = (const float*)d_in[6];
  const float* b0 = (const float*)d_in[7];
  const float* W1s = (const float*)d_in[8];
  const float* W1d = (const float*)d_in[9];
  const float* a1l = (const float*)d_in[10];
  const float* a1r = (const float*)d_in[11];
  const float* b1 = (const float*)d_in[12];
  const float* W2s = (const float*)d_in[13];
  const float* W2d = (const float*)d_in[14];
  const float* a2l = (const float*)d_in[15];
  const float* a2r = (const float*)d_in[16];
  const float* b2 = (const float*)d_in[17];
  float* out = (float*)d_out;

  const int N = in_sizes[0] / 256;  // 100000
  const int E = in_sizes[1];        // 1600000

  char* w = (char*)d_ws;
  size_t off = 0;
  auto alloc = [&](size_t bytes) -> void* {
    void* p = w + off;
    off += (bytes + 255) & ~(size_t)255;
    return p;
  };
  int* gcount = (int*)alloc(4);
  int* cnt = (int*)alloc((size_t)N * 4);
  int* fill = (int*)alloc((size_t)N * 4);
  size_t zbytes = off;  // zero gcount+cnt+fill
  int* row_start = (int*)alloc((size_t)N * 4);
  int* srcs = (int*)alloc((size_t)E * 4);
  float* wlr = (float*)alloc(256 * 8 * 4);
  float* Bpad = (float*)alloc(128 * 192 * 4);
  float* el = (float*)alloc((size_t)N * 4 * 4);
  float* er = (float*)alloc((size_t)N * 4 * 4);
  float* F = (float*)alloc((size_t)N * 192 * 4);
  float* Hb = (float*)alloc((size_t)N * 128 * 4);
  (void)ws_size;

  hipMemsetAsync(d_ws, 0, zbytes, stream);
  k_hist<<<(E + 255) / 256, 256, 0, stream>>>(dst, cnt, E);
  k_offsets<<<(N + 255) / 256, 256, 0, stream>>>(cnt, row_start, gcount, N);
  k_scatter<<<(E + 255) / 256, 256, 0, stream>>>(src, dst, row_start, fill, srcs, E);

  int gemm_grid = (N + 63) / 64;
  int node_grid = (N + 3) / 4;

  // layer 0: K=256
  k_wlr<<<4, 256, 0, stream>>>(W0s, W0d, a0l, a0r, wlr, 256, 32);
  k_gemm<128, 8><<<gemm_grid, 256, 0, stream>>>(x, W0s, F, N, 256);
  k_eler<<<node_grid, 256, 0, stream>>>(x, wlr, el, er, N, 256);
  k_edge_mid<<<node_grid, 256, 0, stream>>>(F, el, er, row_start, cnt, srcs, b0, Hb, N);

  // layer 1: K=128
  k_wlr<<<2, 256, 0, stream>>>(W1s, W1d, a1l, a1r, wlr, 128, 32);
  k_gemm<128, 8><<<gemm_grid, 256, 0, stream>>>(Hb, W1s, F, N, 128);
  k_eler<<<node_grid, 256, 0, stream>>>(Hb, wlr, el, er, N, 128);
  k_edge_mid<<<node_grid, 256, 0, stream>>>(F, el, er, row_start, cnt, srcs, b1, Hb, N);

  // layer 2: K=128, M=188 (padded 192)
  k_wlr<<<2, 256, 0, stream>>>(W2s, W2d, a2l, a2r, wlr, 128, 47);
  k_padw<<<(128 * 192 + 255) / 256, 256, 0, stream>>>(W2s, Bpad, 128);
  k_gemm<192, 12><<<gemm_grid, 256, 0, stream>>>(Hb, Bpad, F, N, 128);
  k_eler<<<node_grid, 256, 0, stream>>>(Hb, wlr, el, er, N, 128);
  k_edge_final<<<node_grid, 256, 0, stream>>>(F, el, er, row_start, cnt, srcs, b2, out, N);
}

// Round 2
// 1049.412 us; speedup vs baseline: 1.3926x; 1.3926x over previous
//
#include <hip/hip_runtime.h>
#include <math.h>

#define NEG_SLOPE 0.2f

typedef _Float16 half2v __attribute__((ext_vector_type(2)));
typedef _Float16 half4v __attribute__((ext_vector_type(4)));

__device__ __forceinline__ float lrelu(float x) { return x > 0.f ? x : NEG_SLOPE * x; }

__device__ __forceinline__ float sel4(const float4 v, int h) {
  float r = v.x;
  r = (h == 1) ? v.y : r;
  r = (h == 2) ? v.z : r;
  r = (h == 3) ? v.w : r;
  return r;
}

// ---------------- CSR build ----------------

__global__ void k_hist(const int* __restrict__ dst, int* __restrict__ cnt, int E) {
  int i = blockIdx.x * blockDim.x + threadIdx.x;
  if (i < E) atomicAdd(&cnt[dst[i]], 1);
}

__global__ __launch_bounds__(256) void k_offsets(const int* __restrict__ cnt,
                                                 int* __restrict__ row_start,
                                                 int* __restrict__ gcount, int N) {
  __shared__ int s[256];
  __shared__ int base;
  int tid = threadIdx.x;
  int i = blockIdx.x * 256 + tid;
  int c = (i < N) ? cnt[i] : 0;
  s[tid] = c;
  __syncthreads();
  for (int off = 1; off < 256; off <<= 1) {
    int v = 0;
    if (tid >= off) v = s[tid - off];
    __syncthreads();
    if (tid >= off) s[tid] += v;
    __syncthreads();
  }
  if (tid == 255) base = atomicAdd(gcount, s[255]);
  __syncthreads();
  if (i < N) row_start[i] = base + s[tid] - c;
}

__global__ void k_scatter(const int* __restrict__ src, const int* __restrict__ dst,
                          const int* __restrict__ row_start, int* __restrict__ fill,
                          int* __restrict__ srcs, int E) {
  int i = blockIdx.x * blockDim.x + threadIdx.x;
  if (i < E) {
    int d = dst[i];
    int p = row_start[d] + atomicAdd(&fill[d], 1);
    srcs[p] = src[i];
  }
}

// ---------------- attention weight folding ----------------
__global__ void k_wlr(const float* __restrict__ Ws, const float* __restrict__ Wd,
                      const float* __restrict__ al, const float* __restrict__ ar,
                      float* __restrict__ wlr, int K, int Dh) {
  int i = blockIdx.x * blockDim.x + threadIdx.x;
  int M = 4 * Dh;
  if (i < K * 4) {
    int k = i >> 2, h = i & 3;
    float sl = 0.f, sr = 0.f;
    for (int d = 0; d < Dh; d++) {
      sl += Ws[(size_t)k * M + h * Dh + d] * al[h * Dh + d];
      sr += Wd[(size_t)k * M + h * Dh + d] * ar[h * Dh + d];
    }
    wlr[k * 8 + h] = sl;
    wlr[k * 8 + 4 + h] = sr;
  }
}

__global__ void k_padw(const float* __restrict__ W, float* __restrict__ Wp, int K) {
  int i = blockIdx.x * blockDim.x + threadIdx.x;  // over K*192
  if (i < K * 192) {
    int k = i / 192, c = i % 192;
    Wp[i] = (c < 188) ? W[(size_t)k * 188 + c] : 0.f;
  }
}

// ---------------- el/er: h @ wlr  ([N,K] x [K,8]) ----------------
__global__ __launch_bounds__(256) void k_eler(const float* __restrict__ H,
                                              const float* __restrict__ wlr,
                                              float* __restrict__ el, float* __restrict__ er,
                                              int N, int K) {
  __shared__ float ws[2048];
  for (int i = threadIdx.x; i < K * 8; i += 256) ws[i] = wlr[i];
  __syncthreads();
  int lane = threadIdx.x & 63;
  int node = blockIdx.x * 4 + (threadIdx.x >> 6);
  if (node >= N) return;
  float p[8] = {0, 0, 0, 0, 0, 0, 0, 0};
  for (int k = lane; k < K; k += 64) {
    float hv = H[(size_t)node * K + k];
#pragma unroll
    for (int j = 0; j < 8; j++) p[j] += hv * ws[k * 8 + j];
  }
#pragma unroll
  for (int j = 0; j < 8; j++) {
#pragma unroll
    for (int m = 1; m < 64; m <<= 1) p[j] += __shfl_xor(p[j], m);
  }
  if (lane == 0) {
    *(float4*)&el[(size_t)node * 4] = make_float4(p[0], p[1], p[2], p[3]);
    *(float4*)&er[(size_t)node * 4] = make_float4(p[4], p[5], p[6], p[7]);
  }
}

// ---------------- fp32 GEMM: C[N,BN] = A[N,K] @ B[K,BN], C stored fp16 ----------------
template <int BN, int TN>
__global__ __launch_bounds__(256) void k_gemm(const float* __restrict__ A,
                                              const float* __restrict__ B,
                                              _Float16* __restrict__ C, int N, int K) {
  __shared__ float As[32][68];
  __shared__ float Bs[32][BN];
  const int tid = threadIdx.x;
  const int tx = tid & 15, ty = tid >> 4;
  const int row0 = blockIdx.x * 64;
  float acc[4][TN];
#pragma unroll
  for (int i = 0; i < 4; i++)
#pragma unroll
    for (int j = 0; j < TN; j++) acc[i][j] = 0.f;

  for (int k0 = 0; k0 < K; k0 += 32) {
#pragma unroll
    for (int i = 0; i < 2; i++) {
      int idx = tid + i * 256;  // [0,512)
      int r = idx >> 3, kq = idx & 7;
      int grow = row0 + r;
      float4 v = make_float4(0.f, 0.f, 0.f, 0.f);
      if (grow < N) v = *(const float4*)&A[(size_t)grow * K + k0 + kq * 4];
      As[kq * 4 + 0][r] = v.x;
      As[kq * 4 + 1][r] = v.y;
      As[kq * 4 + 2][r] = v.z;
      As[kq * 4 + 3][r] = v.w;
    }
#pragma unroll
    for (int i = 0; i < BN / 32; i++) {
      int idx = tid + i * 256;
      int kr = idx / (BN / 4), c4 = idx % (BN / 4);
      *(float4*)&Bs[kr][c4 * 4] = *(const float4*)&B[(size_t)(k0 + kr) * BN + c4 * 4];
    }
    __syncthreads();
#pragma unroll
    for (int kk = 0; kk < 32; kk++) {
      float4 a = *(const float4*)&As[kk][ty * 4];
      float av[4] = {a.x, a.y, a.z, a.w};
      float bv[TN];
#pragma unroll
      for (int j = 0; j < TN / 4; j++) *(float4*)&bv[j * 4] = *(const float4*)&Bs[kk][tx * TN + j * 4];
#pragma unroll
      for (int i = 0; i < 4; i++)
#pragma unroll
        for (int j = 0; j < TN; j++) acc[i][j] += av[i] * bv[j];
    }
    __syncthreads();
  }
#pragma unroll
  for (int i = 0; i < 4; i++) {
    int grow = row0 + ty * 4 + i;
    if (grow < N) {
#pragma unroll
      for (int j = 0; j < TN / 4; j++) {
        half4v o;
        o[0] = (_Float16)acc[i][j * 4 + 0];
        o[1] = (_Float16)acc[i][j * 4 + 1];
        o[2] = (_Float16)acc[i][j * 4 + 2];
        o[3] = (_Float16)acc[i][j * 4 + 3];
        *(half4v*)&C[(size_t)grow * BN + tx * TN + j * 4] = o;
      }
    }
  }
}

// ---------------- edge aggregation, layers 0/1 (M=128 fp16, relu epilogue) ----------------
// No max pass: logits ~N(0,0.23^2), exp cannot overflow; alpha is shift-invariant.
__global__ __launch_bounds__(256) void k_edge_mid(
    const _Float16* __restrict__ F, const float* __restrict__ el, const float* __restrict__ er,
    const int* __restrict__ row_start, const int* __restrict__ cnt, const int* __restrict__ srcs,
    const float* __restrict__ bias, float* __restrict__ hout, int N) {
  __shared__ float sEz[4][64][4];
  __shared__ int sU[4][64];
  int lane = threadIdx.x & 63;
  int w = threadIdx.x >> 6;
  int v = blockIdx.x * 4 + w;
  if (v >= N) return;
  int start = row_start[v], deg = cnt[v];
  float4 erv = *(const float4*)&er[(size_t)v * 4];
  int h = lane >> 4;
  float2 acc = make_float2(0.f, 0.f);
  float4 lsum = make_float4(0.f, 0.f, 0.f, 0.f);

  for (int c = 0; c < deg; c += 64) {
    int take = min(64, deg - c);
    if (lane < take) {
      int u = srcs[start + c + lane];
      float4 e = *(const float4*)&el[(size_t)u * 4];
      float4 ez;
      ez.x = __expf(lrelu(e.x + erv.x));
      ez.y = __expf(lrelu(e.y + erv.y));
      ez.z = __expf(lrelu(e.z + erv.z));
      ez.w = __expf(lrelu(e.w + erv.w));
      lsum.x += ez.x; lsum.y += ez.y; lsum.z += ez.z; lsum.w += ez.w;
      sU[w][lane] = u;
      *(float4*)&sEz[w][lane][0] = ez;
    }
    // wave-private LDS region: same wave wrote it, in-order via lgkmcnt; no barrier.
    for (int kk = 0; kk < take; kk++) {
      int u = sU[w][kk];
      float ezh = sEz[w][kk][h];
      half2v f = *(const half2v*)&F[(size_t)u * 128 + 2 * lane];
      acc.x += ezh * (float)f[0];
      acc.y += ezh * (float)f[1];
    }
  }
#pragma unroll
  for (int msk = 1; msk < 64; msk <<= 1) {
    lsum.x += __shfl_xor(lsum.x, msk);
    lsum.y += __shfl_xor(lsum.y, msk);
    lsum.z += __shfl_xor(lsum.z, msk);
    lsum.w += __shfl_xor(lsum.w, msk);
  }
  float2 bv = *(const float2*)&bias[2 * lane];
  float2 r;
  if (deg > 0) {
    float inv = 1.f / sel4(lsum, h);
    r.x = acc.x * inv + bv.x;
    r.y = acc.y * inv + bv.y;
  } else {
    r = bv;
  }
  r.x = fmaxf(r.x, 0.f);
  r.y = fmaxf(r.y, 0.f);
  *(float2*)&hout[(size_t)v * 128 + 2 * lane] = r;
}

// ---------------- edge aggregation, layer 2 (M=188 fp16, stride 192) + mean + log_softmax ----------------
__global__ __launch_bounds__(256) void k_edge_final(
    const _Float16* __restrict__ F, const float* __restrict__ el, const float* __restrict__ er,
    const int* __restrict__ row_start, const int* __restrict__ cnt, const int* __restrict__ srcs,
    const float* __restrict__ b2, float* __restrict__ out, int N) {
  __shared__ float sEz[4][64][4];
  __shared__ int sU[4][64];
  __shared__ float red[4][188];
  int lane = threadIdx.x & 63;
  int w = threadIdx.x >> 6;
  int v = blockIdx.x * 4 + w;
  if (v >= N) return;  // N%4==0 -> никогда; keeps generality
  int start = row_start[v], deg = cnt[v];
  float4 erv = *(const float4*)&er[(size_t)v * 4];

  int f0 = 2 * lane;        // [0,128)
  int f2 = 128 + 2 * lane;  // [128,188) for lane<30
  int ha = f0 / 47, hb = (f0 + 1) / 47;
  int hc = f2 / 47, hd = (f2 + 1) / 47;
  float2 accA = make_float2(0.f, 0.f), accB = make_float2(0.f, 0.f);
  float4 lsum = make_float4(0.f, 0.f, 0.f, 0.f);

  for (int c = 0; c < deg; c += 64) {
    int take = min(64, deg - c);
    if (lane < take) {
      int u = srcs[start + c + lane];
      float4 e = *(const float4*)&el[(size_t)u * 4];
      float4 ez;
      ez.x = __expf(lrelu(e.x + erv.x));
      ez.y = __expf(lrelu(e.y + erv.y));
      ez.z = __expf(lrelu(e.z + erv.z));
      ez.w = __expf(lrelu(e.w + erv.w));
      lsum.x += ez.x; lsum.y += ez.y; lsum.z += ez.z; lsum.w += ez.w;
      sU[w][lane] = u;
      *(float4*)&sEz[w][lane][0] = ez;
    }
    for (int kk = 0; kk < take; kk++) {
      int u = sU[w][kk];
      half2v fa = *(const half2v*)&F[(size_t)u * 192 + f0];
      accA.x += sEz[w][kk][ha] * (float)fa[0];
      accA.y += sEz[w][kk][hb] * (float)fa[1];
      if (lane < 30) {
        half2v fb = *(const half2v*)&F[(size_t)u * 192 + f2];
        accB.x += sEz[w][kk][hc] * (float)fb[0];
        accB.y += sEz[w][kk][hd] * (float)fb[1];
      }
    }
  }
#pragma unroll
  for (int msk = 1; msk < 64; msk <<= 1) {
    lsum.x += __shfl_xor(lsum.x, msk);
    lsum.y += __shfl_xor(lsum.y, msk);
    lsum.z += __shfl_xor(lsum.z, msk);
    lsum.w += __shfl_xor(lsum.w, msk);
  }
  if (deg > 0) {
    red[w][f0] = accA.x / sel4(lsum, ha) + b2[f0];
    red[w][f0 + 1] = accA.y / sel4(lsum, hb) + b2[f0 + 1];
    if (lane < 30) {
      red[w][f2] = accB.x / sel4(lsum, hc) + b2[f2];
      red[w][f2 + 1] = accB.y / sel4(lsum, hd) + b2[f2 + 1];
    }
  } else {
    red[w][f0] = b2[f0];
    red[w][f0 + 1] = b2[f0 + 1];
    if (lane < 30) {
      red[w][f2] = b2[f2];
      red[w][f2 + 1] = b2[f2 + 1];
    }
  }
  __syncthreads();
  float g = -INFINITY;
  if (lane < 47)
    g = 0.25f * (red[w][lane] + red[w][lane + 47] + red[w][lane + 94] + red[w][lane + 141]);
  float gm = g;
#pragma unroll
  for (int msk = 1; msk < 64; msk <<= 1) gm = fmaxf(gm, __shfl_xor(gm, msk));
  float ex = (lane < 47) ? __expf(g - gm) : 0.f;
  float s = ex;
#pragma unroll
  for (int msk = 1; msk < 64; msk <<= 1) s += __shfl_xor(s, msk);
  if (lane < 47) out[(size_t)v * 47 + lane] = g - gm - __logf(s);
}

// ---------------- launch ----------------
extern "C" void kernel_launch(void* const* d_in, const int* in_sizes, int n_in,
                              void* d_out, int out_size, void* d_ws, size_t ws_size,
                              hipStream_t stream) {
  const float* x = (const float*)d_in[0];
  const int* src = (const int*)d_in[1];
  const int* dst = (const int*)d_in[2];
  const float* W0s = (const float*)d_in[3];
  const float* W0d = (const float*)d_in[4];
  const float* a0l = (const float*)d_in[5];
  const float* a0r = (const float*)d_in[6];
  const float* b0 = (const float*)d_in[7];
  const float* W1s = (const float*)d_in[8];
  const float* W1d = (const float*)d_in[9];
  const float* a1l = (const float*)d_in[10];
  const float* a1r = (const float*)d_in[11];
  const float* b1 = (const float*)d_in[12];
  const float* W2s = (const float*)d_in[13];
  const float* W2d = (const float*)d_in[14];
  const float* a2l = (const float*)d_in[15];
  const float* a2r = (const float*)d_in[16];
  const float* b2 = (const float*)d_in[17];
  float* out = (float*)d_out;

  const int N = in_sizes[0] / 256;  // 100000
  const int E = in_sizes[1];        // 1600000

  char* w = (char*)d_ws;
  size_t off = 0;
  auto alloc = [&](size_t bytes) -> void* {
    void* p = w + off;
    off += (bytes + 255) & ~(size_t)255;
    return p;
  };
  int* gcount = (int*)alloc(4);
  int* cnt = (int*)alloc((size_t)N * 4);
  int* fill = (int*)alloc((size_t)N * 4);
  size_t zbytes = off;  // zero gcount+cnt+fill
  int* row_start = (int*)alloc((size_t)N * 4);
  int* srcs = (int*)alloc((size_t)E * 4);
  float* wlr = (float*)alloc(256 * 8 * 4);
  float* Bpad = (float*)alloc(128 * 192 * 4);
  float* el = (float*)alloc((size_t)N * 4 * 4);
  float* er = (float*)alloc((size_t)N * 4 * 4);
  _Float16* F = (_Float16*)alloc((size_t)N * 192 * 2);
  float* Hb = (float*)alloc((size_t)N * 128 * 4);
  (void)ws_size;

  hipMemsetAsync(d_ws, 0, zbytes, stream);
  k_hist<<<(E + 255) / 256, 256, 0, stream>>>(dst, cnt, E);
  k_offsets<<<(N + 255) / 256, 256, 0, stream>>>(cnt, row_start, gcount, N);
  k_scatter<<<(E + 255) / 256, 256, 0, stream>>>(src, dst, row_start, fill, srcs, E);

  int gemm_grid = (N + 63) / 64;
  int node_grid = (N + 3) / 4;

  // layer 0: K=256
  k_wlr<<<4, 256, 0, stream>>>(W0s, W0d, a0l, a0r, wlr, 256, 32);
  k_gemm<128, 8><<<gemm_grid, 256, 0, stream>>>(x, W0s, F, N, 256);
  k_eler<<<node_grid, 256, 0, stream>>>(x, wlr, el, er, N, 256);
  k_edge_mid<<<node_grid, 256, 0, stream>>>(F, el, er, row_start, cnt, srcs, b0, Hb, N);

  // layer 1: K=128
  k_wlr<<<2, 256, 0, stream>>>(W1s, W1d, a1l, a1r, wlr, 128, 32);
  k_gemm<128, 8><<<gemm_grid, 256, 0, stream>>>(Hb, W1s, F, N, 128);
  k_eler<<<node_grid, 256, 0, stream>>>(Hb, wlr, el, er, N, 128);
  k_edge_mid<<<node_grid, 256, 0, stream>>>(F, el, er, row_start, cnt, srcs, b1, Hb, N);

  // layer 2: K=128, M=188 (padded 192)
  k_wlr<<<2, 256, 0, stream>>>(W2s, W2d, a2l, a2r, wlr, 128, 47);
  k_padw<<<(128 * 192 + 255) / 256, 256, 0, stream>>>(W2s, Bpad, 128);
  k_gemm<192, 12><<<gemm_grid, 256, 0, stream>>>(Hb, Bpad, F, N, 128);
  k_eler<<<node_grid, 256, 0, stream>>>(Hb, wlr, el, er, N, 128);
  k_edge_final<<<node_grid, 256, 0, stream>>>(F, el, er, row_start, cnt, srcs, b2, out, N);
}

// Round 3
// 926.343 us; speedup vs baseline: 1.5776x; 1.1329x over previous
//
#include <hip/hip_runtime.h>
#include <math.h>

#define NEG_SLOPE 0.2f

typedef _Float16 half2v __attribute__((ext_vector_type(2)));
typedef _Float16 half8 __attribute__((ext_vector_type(8)));
typedef float float4v __attribute__((ext_vector_type(4)));

__device__ __forceinline__ float lrelu(float x) { return x > 0.f ? x : NEG_SLOPE * x; }

__device__ __forceinline__ float sel4(const float4 v, int h) {
  float r = v.x;
  r = (h == 1) ? v.y : r;
  r = (h == 2) ? v.z : r;
  r = (h == 3) ? v.w : r;
  return r;
}

// ---------------- CSR build ----------------

__global__ void k_hist(const int* __restrict__ dst, int* __restrict__ cnt, int E) {
  int i = blockIdx.x * blockDim.x + threadIdx.x;
  if (i < E) atomicAdd(&cnt[dst[i]], 1);
}

__global__ __launch_bounds__(256) void k_offsets(const int* __restrict__ cnt,
                                                 int* __restrict__ row_start,
                                                 int* __restrict__ gcount, int N) {
  __shared__ int s[256];
  __shared__ int base;
  int tid = threadIdx.x;
  int i = blockIdx.x * 256 + tid;
  int c = (i < N) ? cnt[i] : 0;
  s[tid] = c;
  __syncthreads();
  for (int off = 1; off < 256; off <<= 1) {
    int v = 0;
    if (tid >= off) v = s[tid - off];
    __syncthreads();
    if (tid >= off) s[tid] += v;
    __syncthreads();
  }
  if (tid == 255) base = atomicAdd(gcount, s[255]);
  __syncthreads();
  if (i < N) row_start[i] = base + s[tid] - c;
}

__global__ void k_scatter(const int* __restrict__ src, const int* __restrict__ dst,
                          const int* __restrict__ row_start, int* __restrict__ fill,
                          int* __restrict__ srcs, int E) {
  int i = blockIdx.x * blockDim.x + threadIdx.x;
  if (i < E) {
    int d = dst[i];
    int p = row_start[d] + atomicAdd(&fill[d], 1);
    srcs[p] = src[i];
  }
}

// ---------------- attention weight folding ----------------
__global__ void k_wlr(const float* __restrict__ Ws, const float* __restrict__ Wd,
                      const float* __restrict__ al, const float* __restrict__ ar,
                      float* __restrict__ wlr, int K, int Dh) {
  int i = blockIdx.x * blockDim.x + threadIdx.x;
  int M = 4 * Dh;
  if (i < K * 4) {
    int k = i >> 2, h = i & 3;
    float sl = 0.f, sr = 0.f;
    for (int d = 0; d < Dh; d++) {
      sl += Ws[(size_t)k * M + h * Dh + d] * al[h * Dh + d];
      sr += Wd[(size_t)k * M + h * Dh + d] * ar[h * Dh + d];
    }
    wlr[k * 8 + h] = sl;
    wlr[k * 8 + 4 + h] = sr;
  }
}

// W[K][M] fp32 -> Wt[Mp][K] fp16 (rows M..Mp zero)
__global__ void k_transw(const float* __restrict__ W, _Float16* __restrict__ Wt,
                         int K, int M, int Mp) {
  int i = blockIdx.x * blockDim.x + threadIdx.x;
  if (i < Mp * K) {
    int m = i / K, k = i % K;
    float v = (m < M) ? W[(size_t)k * M + m] : 0.f;
    Wt[i] = (_Float16)v;
  }
}

// ---------------- el/er: h @ wlr  ([N,K] x [K,8]) ----------------
template <typename T>
__global__ __launch_bounds__(256) void k_eler(const T* __restrict__ H,
                                              const float* __restrict__ wlr,
                                              float* __restrict__ el, float* __restrict__ er,
                                              int N, int K) {
  __shared__ float ws[2048];
  for (int i = threadIdx.x; i < K * 8; i += 256) ws[i] = wlr[i];
  __syncthreads();
  int lane = threadIdx.x & 63;
  int node = blockIdx.x * 4 + (threadIdx.x >> 6);
  if (node >= N) return;
  float p[8] = {0, 0, 0, 0, 0, 0, 0, 0};
  for (int k = lane; k < K; k += 64) {
    float hv = (float)H[(size_t)node * K + k];
#pragma unroll
    for (int j = 0; j < 8; j++) p[j] += hv * ws[k * 8 + j];
  }
#pragma unroll
  for (int j = 0; j < 8; j++) {
#pragma unroll
    for (int m = 1; m < 64; m <<= 1) p[j] += __shfl_xor(p[j], m);
  }
  if (lane == 0) {
    *(float4*)&el[(size_t)node * 4] = make_float4(p[0], p[1], p[2], p[3]);
    *(float4*)&er[(size_t)node * 4] = make_float4(p[4], p[5], p[6], p[7]);
  }
}

// ---------------- MFMA fp16 GEMM: C[N,BN] = A[N,K] @ Wt^T, C fp16 ----------------
// Block: 64 rows x BN cols, 256 threads (4 waves). Wave w covers cols [w*NT*16, ...).
// LDS holds A/B fragments in exact mfma operand layout: frag[tile][lane][8 fp16].
template <int BN, typename AT>
__global__ __launch_bounds__(256) void k_gemm_mfma(const AT* __restrict__ A,
                                                   const _Float16* __restrict__ Bt,
                                                   _Float16* __restrict__ C, int N, int K) {
  constexpr int NT = BN / 64;                 // n-tiles per wave (2 or 3)
  constexpr int ASZ = 4 * 64 * 8;             // 2048 fp16
  constexpr int BSZ = (BN / 16) * 64 * 8;     // 4096 or 6144 fp16
  constexpr int SSZ = (ASZ + BSZ) > (64 * BN) ? (ASZ + BSZ) : (64 * BN);
  __shared__ _Float16 smem[SSZ];
  _Float16* As = smem;
  _Float16* Bs = smem + ASZ;

  const int tid = threadIdx.x;
  const int lane = tid & 63;
  const int w = tid >> 6;
  const int row0 = blockIdx.x * 64;

  float4v acc[4][NT];
#pragma unroll
  for (int i = 0; i < 4; i++)
#pragma unroll
    for (int j = 0; j < NT; j++) acc[i][j] = (float4v){0.f, 0.f, 0.f, 0.f};

  for (int k0 = 0; k0 < K; k0 += 32) {
    // stage A fragment: thread (r = tid>>2, q = tid&3) loads A[row0+r][k0+q*8 .. +8]
    {
      int r = tid >> 2, q = tid & 3;
      int gr = row0 + r;
      half8 v;
      if (gr < N) {
        if constexpr (sizeof(AT) == 4) {
          const float4* p = (const float4*)&A[(size_t)gr * K + k0 + q * 8];
          float4 u0 = p[0], u1 = p[1];
          v[0] = (_Float16)u0.x; v[1] = (_Float16)u0.y; v[2] = (_Float16)u0.z; v[3] = (_Float16)u0.w;
          v[4] = (_Float16)u1.x; v[5] = (_Float16)u1.y; v[6] = (_Float16)u1.z; v[7] = (_Float16)u1.w;
        } else {
          v = *(const half8*)&A[(size_t)gr * K + k0 + q * 8];
        }
      } else {
#pragma unroll
        for (int j = 0; j < 8; j++) v[j] = (_Float16)0.f;
      }
      *(half8*)&As[(size_t)(((r >> 4) * 64) + (r & 15) + 16 * q) * 8] = v;
    }
    // stage B fragment from Wt[n][k]
#pragma unroll
    for (int i = 0; i < NT; i++) {
      int idx = tid + i * 256;
      int n = idx >> 2, q = idx & 3;
      half8 v = *(const half8*)&Bt[(size_t)n * K + k0 + q * 8];
      *(half8*)&Bs[(size_t)((n >> 4) * 64 + (n & 15) + 16 * q) * 8] = v;
    }
    __syncthreads();
    half8 af[4];
#pragma unroll
    for (int mt = 0; mt < 4; mt++) af[mt] = *(half8*)&As[(size_t)(mt * 64 + lane) * 8];
#pragma unroll
    for (int nt = 0; nt < NT; nt++) {
      half8 bf = *(half8*)&Bs[(size_t)((w * NT + nt) * 64 + lane) * 8];
#pragma unroll
      for (int mt = 0; mt < 4; mt++)
        acc[mt][nt] = __builtin_amdgcn_mfma_f32_16x16x32_f16(af[mt], bf, acc[mt][nt], 0, 0, 0);
    }
    __syncthreads();
  }

  // epilogue: C/D layout col=lane&15, row=quad*4+reg -> LDS retile -> coalesced store
  const int quad = lane >> 4;
#pragma unroll
  for (int mt = 0; mt < 4; mt++)
#pragma unroll
    for (int nt = 0; nt < NT; nt++)
#pragma unroll
      for (int reg = 0; reg < 4; reg++) {
        int r = mt * 16 + quad * 4 + reg;
        int cc = (w * NT + nt) * 16 + (lane & 15);
        smem[r * BN + cc] = (_Float16)acc[mt][nt][reg];
      }
  __syncthreads();
  constexpr int PER = (64 * BN) / (256 * 8);
#pragma unroll
  for (int i = 0; i < PER; i++) {
    int idx = tid + i * 256;
    int r = idx / (BN / 8), c8 = idx % (BN / 8);
    int gr = row0 + r;
    if (gr < N) *(half8*)&C[(size_t)gr * BN + c8 * 8] = *(half8*)&smem[r * BN + c8 * 8];
  }
}

// ---------------- edge aggregation, layers 0/1 (M=128 fp16, relu epilogue, fp16 out) ----------------
__global__ __launch_bounds__(256) void k_edge_mid(
    const _Float16* __restrict__ F, const float* __restrict__ el, const float* __restrict__ er,
    const int* __restrict__ row_start, const int* __restrict__ cnt, const int* __restrict__ srcs,
    const float* __restrict__ bias, _Float16* __restrict__ hout, int N) {
  __shared__ float sEz[4][64][4];
  __shared__ int sU[4][64];
  int lane = threadIdx.x & 63;
  int w = threadIdx.x >> 6;
  int v = blockIdx.x * 4 + w;
  if (v >= N) return;
  int start = row_start[v], deg = cnt[v];
  float4 erv = *(const float4*)&er[(size_t)v * 4];
  int h = lane >> 4;
  float2 acc = make_float2(0.f, 0.f);
  float4 lsum = make_float4(0.f, 0.f, 0.f, 0.f);

  for (int c = 0; c < deg; c += 64) {
    int take = min(64, deg - c);
    if (lane < take) {
      int u = srcs[start + c + lane];
      float4 e = *(const float4*)&el[(size_t)u * 4];
      float4 ez;
      ez.x = __expf(lrelu(e.x + erv.x));
      ez.y = __expf(lrelu(e.y + erv.y));
      ez.z = __expf(lrelu(e.z + erv.z));
      ez.w = __expf(lrelu(e.w + erv.w));
      lsum.x += ez.x; lsum.y += ez.y; lsum.z += ez.z; lsum.w += ez.w;
      sU[w][lane] = u;
      *(float4*)&sEz[w][lane][0] = ez;
    }
    // wave-private LDS region: in-order via lgkmcnt; no barrier needed.
    for (int kk = 0; kk < take; kk++) {
      int u = sU[w][kk];
      float ezh = sEz[w][kk][h];
      half2v f = *(const half2v*)&F[(size_t)u * 128 + 2 * lane];
      acc.x += ezh * (float)f[0];
      acc.y += ezh * (float)f[1];
    }
  }
#pragma unroll
  for (int msk = 1; msk < 64; msk <<= 1) {
    lsum.x += __shfl_xor(lsum.x, msk);
    lsum.y += __shfl_xor(lsum.y, msk);
    lsum.z += __shfl_xor(lsum.z, msk);
    lsum.w += __shfl_xor(lsum.w, msk);
  }
  float2 bv = *(const float2*)&bias[2 * lane];
  float2 r;
  if (deg > 0) {
    float inv = 1.f / sel4(lsum, h);
    r.x = acc.x * inv + bv.x;
    r.y = acc.y * inv + bv.y;
  } else {
    r = bv;
  }
  half2v o;
  o[0] = (_Float16)fmaxf(r.x, 0.f);
  o[1] = (_Float16)fmaxf(r.y, 0.f);
  *(half2v*)&hout[(size_t)v * 128 + 2 * lane] = o;
}

// ---------------- edge aggregation, layer 2 (M=188 fp16, stride 192) + mean + log_softmax ----------------
__global__ __launch_bounds__(256) void k_edge_final(
    const _Float16* __restrict__ F, const float* __restrict__ el, const float* __restrict__ er,
    const int* __restrict__ row_start, const int* __restrict__ cnt, const int* __restrict__ srcs,
    const float* __restrict__ b2, float* __restrict__ out, int N) {
  __shared__ float sEz[4][64][4];
  __shared__ int sU[4][64];
  __shared__ float red[4][188];
  int lane = threadIdx.x & 63;
  int w = threadIdx.x >> 6;
  int v = blockIdx.x * 4 + w;
  if (v >= N) return;
  int start = row_start[v], deg = cnt[v];
  float4 erv = *(const float4*)&er[(size_t)v * 4];

  int f0 = 2 * lane;        // [0,128)
  int f2 = 128 + 2 * lane;  // [128,188) for lane<30
  int ha = f0 / 47, hb = (f0 + 1) / 47;
  int hc = f2 / 47, hd = (f2 + 1) / 47;
  float2 accA = make_float2(0.f, 0.f), accB = make_float2(0.f, 0.f);
  float4 lsum = make_float4(0.f, 0.f, 0.f, 0.f);

  for (int c = 0; c < deg; c += 64) {
    int take = min(64, deg - c);
    if (lane < take) {
      int u = srcs[start + c + lane];
      float4 e = *(const float4*)&el[(size_t)u * 4];
      float4 ez;
      ez.x = __expf(lrelu(e.x + erv.x));
      ez.y = __expf(lrelu(e.y + erv.y));
      ez.z = __expf(lrelu(e.z + erv.z));
      ez.w = __expf(lrelu(e.w + erv.w));
      lsum.x += ez.x; lsum.y += ez.y; lsum.z += ez.z; lsum.w += ez.w;
      sU[w][lane] = u;
      *(float4*)&sEz[w][lane][0] = ez;
    }
    for (int kk = 0; kk < take; kk++) {
      int u = sU[w][kk];
      half2v fa = *(const half2v*)&F[(size_t)u * 192 + f0];
      accA.x += sEz[w][kk][ha] * (float)fa[0];
      accA.y += sEz[w][kk][hb] * (float)fa[1];
      if (lane < 30) {
        half2v fb = *(const half2v*)&F[(size_t)u * 192 + f2];
        accB.x += sEz[w][kk][hc] * (float)fb[0];
        accB.y += sEz[w][kk][hd] * (float)fb[1];
      }
    }
  }
#pragma unroll
  for (int msk = 1; msk < 64; msk <<= 1) {
    lsum.x += __shfl_xor(lsum.x, msk);
    lsum.y += __shfl_xor(lsum.y, msk);
    lsum.z += __shfl_xor(lsum.z, msk);
    lsum.w += __shfl_xor(lsum.w, msk);
  }
  if (deg > 0) {
    red[w][f0] = accA.x / sel4(lsum, ha) + b2[f0];
    red[w][f0 + 1] = accA.y / sel4(lsum, hb) + b2[f0 + 1];
    if (lane < 30) {
      red[w][f2] = accB.x / sel4(lsum, hc) + b2[f2];
      red[w][f2 + 1] = accB.y / sel4(lsum, hd) + b2[f2 + 1];
    }
  } else {
    red[w][f0] = b2[f0];
    red[w][f0 + 1] = b2[f0 + 1];
    if (lane < 30) {
      red[w][f2] = b2[f2];
      red[w][f2 + 1] = b2[f2 + 1];
    }
  }
  __syncthreads();
  float g = -INFINITY;
  if (lane < 47)
    g = 0.25f * (red[w][lane] + red[w][lane + 47] + red[w][lane + 94] + red[w][lane + 141]);
  float gm = g;
#pragma unroll
  for (int msk = 1; msk < 64; msk <<= 1) gm = fmaxf(gm, __shfl_xor(gm, msk));
  float ex = (lane < 47) ? __expf(g - gm) : 0.f;
  float s = ex;
#pragma unroll
  for (int msk = 1; msk < 64; msk <<= 1) s += __shfl_xor(s, msk);
  if (lane < 47) out[(size_t)v * 47 + lane] = g - gm - __logf(s);
}

// ---------------- launch ----------------
extern "C" void kernel_launch(void* const* d_in, const int* in_sizes, int n_in,
                              void* d_out, int out_size, void* d_ws, size_t ws_size,
                              hipStream_t stream) {
  const float* x = (const float*)d_in[0];
  const int* src = (const int*)d_in[1];
  const int* dst = (const int*)d_in[2];
  const float* W0s = (const float*)d_in[3];
  const float* W0d = (const float*)d_in[4];
  const float* a0l = (const float*)d_in[5];
  const float* a0r = (const float*)d_in[6];
  const float* b0 = (const float*)d_in[7];
  const float* W1s = (const float*)d_in[8];
  const float* W1d = (const float*)d_in[9];
  const float* a1l = (const float*)d_in[10];
  const float* a1r = (const float*)d_in[11];
  const float* b1 = (const float*)d_in[12];
  const float* W2s = (const float*)d_in[13];
  const float* W2d = (const float*)d_in[14];
  const float* a2l = (const float*)d_in[15];
  const float* a2r = (const float*)d_in[16];
  const float* b2 = (const float*)d_in[17];
  float* out = (float*)d_out;

  const int N = in_sizes[0] / 256;  // 100000
  const int E = in_sizes[1];        // 1600000

  char* w = (char*)d_ws;
  size_t off = 0;
  auto alloc = [&](size_t bytes) -> void* {
    void* p = w + off;
    off += (bytes + 255) & ~(size_t)255;
    return p;
  };
  int* gcount = (int*)alloc(4);
  int* cnt = (int*)alloc((size_t)N * 4);
  int* fill = (int*)alloc((size_t)N * 4);
  size_t zbytes = off;  // zero gcount+cnt+fill
  int* row_start = (int*)alloc((size_t)N * 4);
  int* srcs = (int*)alloc((size_t)E * 4);
  float* wlr = (float*)alloc(256 * 8 * 4);
  _Float16* Wt = (_Float16*)alloc(192 * 256 * 2);
  float* el = (float*)alloc((size_t)N * 4 * 4);
  float* er = (float*)alloc((size_t)N * 4 * 4);
  _Float16* F = (_Float16*)alloc((size_t)N * 192 * 2);
  _Float16* Ha = (_Float16*)alloc((size_t)N * 128 * 2);
  _Float16* Hc = (_Float16*)alloc((size_t)N * 128 * 2);
  (void)ws_size;

  hipMemsetAsync(d_ws, 0, zbytes, stream);
  k_hist<<<(E + 255) / 256, 256, 0, stream>>>(dst, cnt, E);
  k_offsets<<<(N + 255) / 256, 256, 0, stream>>>(cnt, row_start, gcount, N);
  k_scatter<<<(E + 255) / 256, 256, 0, stream>>>(src, dst, row_start, fill, srcs, E);

  int gemm_grid = (N + 63) / 64;
  int node_grid = (N + 3) / 4;

  // layer 0: K=256, fp32 A (x)
  k_wlr<<<4, 256, 0, stream>>>(W0s, W0d, a0l, a0r, wlr, 256, 32);
  k_transw<<<(128 * 256 + 255) / 256, 256, 0, stream>>>(W0s, Wt, 256, 128, 128);
  k_gemm_mfma<128, float><<<gemm_grid, 256, 0, stream>>>(x, Wt, F, N, 256);
  k_eler<float><<<node_grid, 256, 0, stream>>>(x, wlr, el, er, N, 256);
  k_edge_mid<<<node_grid, 256, 0, stream>>>(F, el, er, row_start, cnt, srcs, b0, Ha, N);

  // layer 1: K=128, fp16 A
  k_wlr<<<2, 256, 0, stream>>>(W1s, W1d, a1l, a1r, wlr, 128, 32);
  k_transw<<<(128 * 128 + 255) / 256, 256, 0, stream>>>(W1s, Wt, 128, 128, 128);
  k_gemm_mfma<128, _Float16><<<gemm_grid, 256, 0, stream>>>(Ha, Wt, F, N, 128);
  k_eler<_Float16><<<node_grid, 256, 0, stream>>>(Ha, wlr, el, er, N, 128);
  k_edge_mid<<<node_grid, 256, 0, stream>>>(F, el, er, row_start, cnt, srcs, b1, Hc, N);

  // layer 2: K=128, M=188 padded to 192, fp16 A
  k_wlr<<<2, 256, 0, stream>>>(W2s, W2d, a2l, a2r, wlr, 128, 47);
  k_transw<<<(192 * 128 + 255) / 256, 256, 0, stream>>>(W2s, Wt, 128, 188, 192);
  k_gemm_mfma<192, _Float16><<<gemm_grid, 256, 0, stream>>>(Hc, Wt, F, N, 128);
  k_eler<_Float16><<<node_grid, 256, 0, stream>>>(Hc, wlr, el, er, N, 128);
  k_edge_final<<<node_grid, 256, 0, stream>>>(F, el, er, row_start, cnt, srcs, b2, out, N);
}

// Round 4
// 889.062 us; speedup vs baseline: 1.6438x; 1.0419x over previous
//
#include <hip/hip_runtime.h>
#include <math.h>

#define NEG_SLOPE 0.2f

typedef _Float16 half2v __attribute__((ext_vector_type(2)));
typedef _Float16 half8 __attribute__((ext_vector_type(8)));
typedef float float4v __attribute__((ext_vector_type(4)));

__device__ __forceinline__ float lrelu(float x) { return x > 0.f ? x : NEG_SLOPE * x; }

__device__ __forceinline__ float sel4(const float4 v, int h) {
  float r = v.x;
  r = (h == 1) ? v.y : r;
  r = (h == 2) ? v.z : r;
  r = (h == 3) ? v.w : r;
  return r;
}

// ---------------- CSR build ----------------

__global__ void k_hist(const int* __restrict__ dst, int* __restrict__ cnt, int E) {
  int i = blockIdx.x * blockDim.x + threadIdx.x;
  if (i < E) atomicAdd(&cnt[dst[i]], 1);
}

__global__ __launch_bounds__(256) void k_offsets(const int* __restrict__ cnt,
                                                 int* __restrict__ row_start,
                                                 int* __restrict__ gcount, int N) {
  __shared__ int s[256];
  __shared__ int base;
  int tid = threadIdx.x;
  int i = blockIdx.x * 256 + tid;
  int c = (i < N) ? cnt[i] : 0;
  s[tid] = c;
  __syncthreads();
  for (int off = 1; off < 256; off <<= 1) {
    int v = 0;
    if (tid >= off) v = s[tid - off];
    __syncthreads();
    if (tid >= off) s[tid] += v;
    __syncthreads();
  }
  if (tid == 255) base = atomicAdd(gcount, s[255]);
  __syncthreads();
  if (i < N) row_start[i] = base + s[tid] - c;
}

__global__ void k_scatter(const int* __restrict__ src, const int* __restrict__ dst,
                          const int* __restrict__ row_start, int* __restrict__ fill,
                          int* __restrict__ srcs, int E) {
  int i = blockIdx.x * blockDim.x + threadIdx.x;
  if (i < E) {
    int d = dst[i];
    int p = row_start[d] + atomicAdd(&fill[d], 1);
    srcs[p] = src[i];
  }
}

// ---------------- attention weight folding ----------------
__global__ void k_wlr(const float* __restrict__ Ws, const float* __restrict__ Wd,
                      const float* __restrict__ al, const float* __restrict__ ar,
                      float* __restrict__ wlr, int K, int Dh) {
  int i = blockIdx.x * blockDim.x + threadIdx.x;
  int M = 4 * Dh;
  if (i < K * 4) {
    int k = i >> 2, h = i & 3;
    float sl = 0.f, sr = 0.f;
    for (int d = 0; d < Dh; d++) {
      sl += Ws[(size_t)k * M + h * Dh + d] * al[h * Dh + d];
      sr += Wd[(size_t)k * M + h * Dh + d] * ar[h * Dh + d];
    }
    wlr[k * 8 + h] = sl;
    wlr[k * 8 + 4 + h] = sr;
  }
}

// W[K][M] fp32 -> Wt[Mp][K] fp16 (rows M..Mp zero)
__global__ void k_transw(const float* __restrict__ W, _Float16* __restrict__ Wt,
                         int K, int M, int Mp) {
  int i = blockIdx.x * blockDim.x + threadIdx.x;
  if (i < Mp * K) {
    int m = i / K, k = i % K;
    float v = (m < M) ? W[(size_t)k * M + m] : 0.f;
    Wt[i] = (_Float16)v;
  }
}

// layer-2 weights: W[K][188] -> Wt[192][K] fp16 with head-padded rows:
// row r = 48*h + c, value = W[k][47*h + c] for c<47, else 0.
__global__ void k_transw2(const float* __restrict__ W, _Float16* __restrict__ Wt, int K) {
  int i = blockIdx.x * blockDim.x + threadIdx.x;
  if (i < 192 * K) {
    int r = i / K, k = i % K;
    int h = r / 48, c = r % 48;
    float v = (c < 47) ? W[(size_t)k * 188 + 47 * h + c] : 0.f;
    Wt[i] = (_Float16)v;
  }
}

// ---------------- el/er: h @ wlr  ([N,K] x [K,8]) ----------------
template <typename T>
__global__ __launch_bounds__(256) void k_eler(const T* __restrict__ H,
                                              const float* __restrict__ wlr,
                                              float* __restrict__ el, float* __restrict__ er,
                                              int N, int K) {
  __shared__ float ws[2048];
  for (int i = threadIdx.x; i < K * 8; i += 256) ws[i] = wlr[i];
  __syncthreads();
  int lane = threadIdx.x & 63;
  int node = blockIdx.x * 4 + (threadIdx.x >> 6);
  if (node >= N) return;
  float p[8] = {0, 0, 0, 0, 0, 0, 0, 0};
  for (int k = lane; k < K; k += 64) {
    float hv = (float)H[(size_t)node * K + k];
#pragma unroll
    for (int j = 0; j < 8; j++) p[j] += hv * ws[k * 8 + j];
  }
#pragma unroll
  for (int j = 0; j < 8; j++) {
#pragma unroll
    for (int m = 1; m < 64; m <<= 1) p[j] += __shfl_xor(p[j], m);
  }
  if (lane == 0) {
    *(float4*)&el[(size_t)node * 4] = make_float4(p[0], p[1], p[2], p[3]);
    *(float4*)&er[(size_t)node * 4] = make_float4(p[4], p[5], p[6], p[7]);
  }
}

// ---------------- MFMA fp16 GEMM: C[N,BN] = A[N,K] @ Wt^T, C fp16 ----------------
template <int BN, typename AT>
__global__ __launch_bounds__(256) void k_gemm_mfma(const AT* __restrict__ A,
                                                   const _Float16* __restrict__ Bt,
                                                   _Float16* __restrict__ C, int N, int K) {
  constexpr int NT = BN / 64;                 // n-tiles per wave (2 or 3)
  constexpr int ASZ = 4 * 64 * 8;             // 2048 fp16
  constexpr int BSZ = (BN / 16) * 64 * 8;     // 4096 or 6144 fp16
  constexpr int SSZ = (ASZ + BSZ) > (64 * BN) ? (ASZ + BSZ) : (64 * BN);
  __shared__ _Float16 smem[SSZ];
  _Float16* As = smem;
  _Float16* Bs = smem + ASZ;

  const int tid = threadIdx.x;
  const int lane = tid & 63;
  const int w = tid >> 6;
  const int row0 = blockIdx.x * 64;

  float4v acc[4][NT];
#pragma unroll
  for (int i = 0; i < 4; i++)
#pragma unroll
    for (int j = 0; j < NT; j++) acc[i][j] = (float4v){0.f, 0.f, 0.f, 0.f};

  for (int k0 = 0; k0 < K; k0 += 32) {
    {
      int r = tid >> 2, q = tid & 3;
      int gr = row0 + r;
      half8 v;
      if (gr < N) {
        if constexpr (sizeof(AT) == 4) {
          const float4* p = (const float4*)&A[(size_t)gr * K + k0 + q * 8];
          float4 u0 = p[0], u1 = p[1];
          v[0] = (_Float16)u0.x; v[1] = (_Float16)u0.y; v[2] = (_Float16)u0.z; v[3] = (_Float16)u0.w;
          v[4] = (_Float16)u1.x; v[5] = (_Float16)u1.y; v[6] = (_Float16)u1.z; v[7] = (_Float16)u1.w;
        } else {
          v = *(const half8*)&A[(size_t)gr * K + k0 + q * 8];
        }
      } else {
#pragma unroll
        for (int j = 0; j < 8; j++) v[j] = (_Float16)0.f;
      }
      *(half8*)&As[(size_t)(((r >> 4) * 64) + (r & 15) + 16 * q) * 8] = v;
    }
#pragma unroll
    for (int i = 0; i < NT; i++) {
      int idx = tid + i * 256;
      int n = idx >> 2, q = idx & 3;
      half8 v = *(const half8*)&Bt[(size_t)n * K + k0 + q * 8];
      *(half8*)&Bs[(size_t)((n >> 4) * 64 + (n & 15) + 16 * q) * 8] = v;
    }
    __syncthreads();
    half8 af[4];
#pragma unroll
    for (int mt = 0; mt < 4; mt++) af[mt] = *(half8*)&As[(size_t)(mt * 64 + lane) * 8];
#pragma unroll
    for (int nt = 0; nt < NT; nt++) {
      half8 bf = *(half8*)&Bs[(size_t)((w * NT + nt) * 64 + lane) * 8];
#pragma unroll
      for (int mt = 0; mt < 4; mt++)
        acc[mt][nt] = __builtin_amdgcn_mfma_f32_16x16x32_f16(af[mt], bf, acc[mt][nt], 0, 0, 0);
    }
    __syncthreads();
  }

  const int quad = lane >> 4;
#pragma unroll
  for (int mt = 0; mt < 4; mt++)
#pragma unroll
    for (int nt = 0; nt < NT; nt++)
#pragma unroll
      for (int reg = 0; reg < 4; reg++) {
        int r = mt * 16 + quad * 4 + reg;
        int cc = (w * NT + nt) * 16 + (lane & 15);
        smem[r * BN + cc] = (_Float16)acc[mt][nt][reg];
      }
  __syncthreads();
  constexpr int PER = (64 * BN) / (256 * 8);
#pragma unroll
  for (int i = 0; i < PER; i++) {
    int idx = tid + i * 256;
    int r = idx / (BN / 8), c8 = idx % (BN / 8);
    int gr = row0 + r;
    if (gr < N) *(half8*)&C[(size_t)gr * BN + c8 * 8] = *(half8*)&smem[r * BN + c8 * 8];
  }
}

// ---------------- edge aggregation, layers 0/1 ----------------
// Quarter-wave scheme: 4 groups of 16 lanes, each group one edge at a time;
// lane owns 8 contiguous features (16B fp16 load). 128 = 16 lanes * 8; head = fl>>2.
__global__ __launch_bounds__(256) void k_edge_mid(
    const _Float16* __restrict__ F, const float* __restrict__ el, const float* __restrict__ er,
    const int* __restrict__ row_start, const int* __restrict__ cnt, const int* __restrict__ srcs,
    const float* __restrict__ bias, _Float16* __restrict__ hout, int N) {
  __shared__ float sEz[4][64][4];
  __shared__ int sU[4][64];
  int lane = threadIdx.x & 63;
  int w = threadIdx.x >> 6;
  int v = blockIdx.x * 4 + w;
  if (v >= N) return;
  int start = row_start[v], deg = cnt[v];
  float4 erv = *(const float4*)&er[(size_t)v * 4];
  const int g = lane >> 4;   // edge subgroup
  const int fl = lane & 15;  // feature slot
  const int h = fl >> 2;     // head of this lane's 8 features
  float acc[8] = {0, 0, 0, 0, 0, 0, 0, 0};
  float4 lsum = make_float4(0.f, 0.f, 0.f, 0.f);

  for (int c = 0; c < deg; c += 64) {
    int take = min(64, deg - c);
    {
      int u = 0;
      float4 ez = make_float4(0.f, 0.f, 0.f, 0.f);
      if (lane < take) {
        u = srcs[start + c + lane];
        float4 e = *(const float4*)&el[(size_t)u * 4];
        ez.x = __expf(lrelu(e.x + erv.x));
        ez.y = __expf(lrelu(e.y + erv.y));
        ez.z = __expf(lrelu(e.z + erv.z));
        ez.w = __expf(lrelu(e.w + erv.w));
        lsum.x += ez.x; lsum.y += ez.y; lsum.z += ez.z; lsum.w += ez.w;
      }
      sU[w][lane] = u;  // pad slots: u=0, ez=0 (harmless dummy row)
      *(float4*)&sEz[w][lane][0] = ez;
    }
    // wave-private LDS region: same-wave in-order via lgkmcnt; no barrier.
    int tp = (take + 3) & ~3;
    for (int kk = g; kk < tp; kk += 4) {
      int u = sU[w][kk];
      float ezh = sEz[w][kk][h];
      half8 f = *(const half8*)&F[(size_t)u * 128 + 8 * fl];
#pragma unroll
      for (int j = 0; j < 8; j++) acc[j] += ezh * (float)f[j];
    }
  }
#pragma unroll
  for (int j = 0; j < 8; j++) {
    acc[j] += __shfl_xor(acc[j], 16);
    acc[j] += __shfl_xor(acc[j], 32);
  }
#pragma unroll
  for (int msk = 1; msk < 64; msk <<= 1) {
    lsum.x += __shfl_xor(lsum.x, msk);
    lsum.y += __shfl_xor(lsum.y, msk);
    lsum.z += __shfl_xor(lsum.z, msk);
    lsum.w += __shfl_xor(lsum.w, msk);
  }
  if (g == 0) {
    float inv = (deg > 0) ? 1.f / sel4(lsum, h) : 0.f;
    const float4* bp = (const float4*)&bias[8 * fl];
    float4 b0v = bp[0], b1v = bp[1];
    float bb[8] = {b0v.x, b0v.y, b0v.z, b0v.w, b1v.x, b1v.y, b1v.z, b1v.w};
    half8 o;
#pragma unroll
    for (int j = 0; j < 8; j++) o[j] = (_Float16)fmaxf(fmaf(acc[j], inv, bb[j]), 0.f);
    *(half8*)&hout[(size_t)v * 128 + 8 * fl] = o;
  }
}

// ---------------- edge aggregation, layer 2 (head-padded 4x48 fp16) + mean + log_softmax ----------------
// Two 24-lane halves (lanes 0-23, 32-55) process edge parities; lane owns 8 feats
// at 48*h + 8*j6 (16B-aligned); pad col c=47 is zero in F.
__global__ __launch_bounds__(256) void k_edge_final(
    const _Float16* __restrict__ F, const float* __restrict__ el, const float* __restrict__ er,
    const int* __restrict__ row_start, const int* __restrict__ cnt, const int* __restrict__ srcs,
    const float* __restrict__ b2, float* __restrict__ out, int N) {
  __shared__ float sEz[4][64][4];
  __shared__ int sU[4][64];
  __shared__ float red[4][192];
  int lane = threadIdx.x & 63;
  int w = threadIdx.x >> 6;
  int v = blockIdx.x * 4 + w;
  if (v >= N) return;
  int start = row_start[v], deg = cnt[v];
  float4 erv = *(const float4*)&er[(size_t)v * 4];
  const int sub = lane >> 5;   // edge parity
  const int l24 = lane & 31;   // 0..31, active if <24
  const bool act = l24 < 24;
  const int h = l24 / 6;       // head (for l24<24)
  const int j6 = l24 % 6;
  const int foff = 48 * h + 8 * j6;
  float acc[8] = {0, 0, 0, 0, 0, 0, 0, 0};
  float4 lsum = make_float4(0.f, 0.f, 0.f, 0.f);

  for (int c = 0; c < deg; c += 64) {
    int take = min(64, deg - c);
    {
      int u = 0;
      float4 ez = make_float4(0.f, 0.f, 0.f, 0.f);
      if (lane < take) {
        u = srcs[start + c + lane];
        float4 e = *(const float4*)&el[(size_t)u * 4];
        ez.x = __expf(lrelu(e.x + erv.x));
        ez.y = __expf(lrelu(e.y + erv.y));
        ez.z = __expf(lrelu(e.z + erv.z));
        ez.w = __expf(lrelu(e.w + erv.w));
        lsum.x += ez.x; lsum.y += ez.y; lsum.z += ez.z; lsum.w += ez.w;
      }
      sU[w][lane] = u;
      *(float4*)&sEz[w][lane][0] = ez;
    }
    int tp = (take + 1) & ~1;
    if (act) {
      for (int kk = sub; kk < tp; kk += 2) {
        int u = sU[w][kk];
        float ezh = sEz[w][kk][h];
        half8 f = *(const half8*)&F[(size_t)u * 192 + foff];
#pragma unroll
        for (int j = 0; j < 8; j++) acc[j] += ezh * (float)f[j];
      }
    }
  }
#pragma unroll
  for (int j = 0; j < 8; j++) acc[j] += __shfl_xor(acc[j], 32);
#pragma unroll
  for (int msk = 1; msk < 64; msk <<= 1) {
    lsum.x += __shfl_xor(lsum.x, msk);
    lsum.y += __shfl_xor(lsum.y, msk);
    lsum.z += __shfl_xor(lsum.z, msk);
    lsum.w += __shfl_xor(lsum.w, msk);
  }
  if (act && sub == 0) {
    float inv = (deg > 0) ? 1.f / sel4(lsum, h) : 0.f;
#pragma unroll
    for (int j = 0; j < 8; j++) {
      int cc = 8 * j6 + j;
      float bv = (cc < 47) ? b2[47 * h + cc] : 0.f;
      red[w][foff + j] = fmaf(acc[j], inv, bv);
    }
  }
  __syncthreads();
  float g = -INFINITY;
  if (lane < 47)
    g = 0.25f * (red[w][lane] + red[w][lane + 48] + red[w][lane + 96] + red[w][lane + 144]);
  float gm = g;
#pragma unroll
  for (int msk = 1; msk < 64; msk <<= 1) gm = fmaxf(gm, __shfl_xor(gm, msk));
  float ex = (lane < 47) ? __expf(g - gm) : 0.f;
  float s = ex;
#pragma unroll
  for (int msk = 1; msk < 64; msk <<= 1) s += __shfl_xor(s, msk);
  if (lane < 47) out[(size_t)v * 47 + lane] = g - gm - __logf(s);
}

// ---------------- launch ----------------
extern "C" void kernel_launch(void* const* d_in, const int* in_sizes, int n_in,
                              void* d_out, int out_size, void* d_ws, size_t ws_size,
                              hipStream_t stream) {
  const float* x = (const float*)d_in[0];
  const int* src = (const int*)d_in[1];
  const int* dst = (const int*)d_in[2];
  const float* W0s = (const float*)d_in[3];
  const float* W0d = (const float*)d_in[4];
  const float* a0l = (const float*)d_in[5];
  const float* a0r = (const float*)d_in[6];
  const float* b0 = (const float*)d_in[7];
  const float* W1s = (const float*)d_in[8];
  const float* W1d = (const float*)d_in[9];
  const float* a1l = (const float*)d_in[10];
  const float* a1r = (const float*)d_in[11];
  const float* b1 = (const float*)d_in[12];
  const float* W2s = (const float*)d_in[13];
  const float* W2d = (const float*)d_in[14];
  const float* a2l = (const float*)d_in[15];
  const float* a2r = (const float*)d_in[16];
  const float* b2 = (const float*)d_in[17];
  float* out = (float*)d_out;

  const int N = in_sizes[0] / 256;  // 100000
  const int E = in_sizes[1];        // 1600000

  char* w = (char*)d_ws;
  size_t off = 0;
  auto alloc = [&](size_t bytes) -> void* {
    void* p = w + off;
    off += (bytes + 255) & ~(size_t)255;
    return p;
  };
  int* gcount = (int*)alloc(4);
  int* cnt = (int*)alloc((size_t)N * 4);
  int* fill = (int*)alloc((size_t)N * 4);
  size_t zbytes = off;  // zero gcount+cnt+fill
  int* row_start = (int*)alloc((size_t)N * 4);
  int* srcs = (int*)alloc((size_t)E * 4);
  float* wlr = (float*)alloc(256 * 8 * 4);
  _Float16* Wt = (_Float16*)alloc(192 * 256 * 2);
  float* el = (float*)alloc((size_t)N * 4 * 4);
  float* er = (float*)alloc((size_t)N * 4 * 4);
  _Float16* F = (_Float16*)alloc((size_t)N * 192 * 2);
  _Float16* Ha = (_Float16*)alloc((size_t)N * 128 * 2);
  _Float16* Hc = (_Float16*)alloc((size_t)N * 128 * 2);
  (void)ws_size;

  hipMemsetAsync(d_ws, 0, zbytes, stream);
  k_hist<<<(E + 255) / 256, 256, 0, stream>>>(dst, cnt, E);
  k_offsets<<<(N + 255) / 256, 256, 0, stream>>>(cnt, row_start, gcount, N);
  k_scatter<<<(E + 255) / 256, 256, 0, stream>>>(src, dst, row_start, fill, srcs, E);

  int gemm_grid = (N + 63) / 64;
  int node_grid = (N + 3) / 4;

  // layer 0: K=256, fp32 A (x)
  k_wlr<<<4, 256, 0, stream>>>(W0s, W0d, a0l, a0r, wlr, 256, 32);
  k_transw<<<(128 * 256 + 255) / 256, 256, 0, stream>>>(W0s, Wt, 256, 128, 128);
  k_gemm_mfma<128, float><<<gemm_grid, 256, 0, stream>>>(x, Wt, F, N, 256);
  k_eler<float><<<node_grid, 256, 0, stream>>>(x, wlr, el, er, N, 256);
  k_edge_mid<<<node_grid, 256, 0, stream>>>(F, el, er, row_start, cnt, srcs, b0, Ha, N);

  // layer 1: K=128, fp16 A
  k_wlr<<<2, 256, 0, stream>>>(W1s, W1d, a1l, a1r, wlr, 128, 32);
  k_transw<<<(128 * 128 + 255) / 256, 256, 0, stream>>>(W1s, Wt, 128, 128, 128);
  k_gemm_mfma<128, _Float16><<<gemm_grid, 256, 0, stream>>>(Ha, Wt, F, N, 128);
  k_eler<_Float16><<<node_grid, 256, 0, stream>>>(Ha, wlr, el, er, N, 128);
  k_edge_mid<<<node_grid, 256, 0, stream>>>(F, el, er, row_start, cnt, srcs, b1, Hc, N);

  // layer 2: K=128, M=192 head-padded (4 x 48, col 47 of each head zero)
  k_wlr<<<2, 256, 0, stream>>>(W2s, W2d, a2l, a2r, wlr, 128, 47);
  k_transw2<<<(192 * 128 + 255) / 256, 256, 0, stream>>>(W2s, Wt, 128);
  k_gemm_mfma<192, _Float16><<<gemm_grid, 256, 0, stream>>>(Hc, Wt, F, N, 128);
  k_eler<_Float16><<<node_grid, 256, 0, stream>>>(Hc, wlr, el, er, N, 128);
  k_edge_final<<<node_grid, 256, 0, stream>>>(F, el, er, row_start, cnt, srcs, b2, out, N);
}

// Round 5
// 680.106 us; speedup vs baseline: 2.1488x; 1.3072x over previous
//
#include <hip/hip_runtime.h>
#include <math.h>

#define NEG_SLOPE 0.2f

typedef _Float16 half2v __attribute__((ext_vector_type(2)));
typedef _Float16 half8 __attribute__((ext_vector_type(8)));
typedef float float4v __attribute__((ext_vector_type(4)));
typedef float float2v __attribute__((ext_vector_type(2)));

__device__ __forceinline__ float lrelu(float x) { return x > 0.f ? x : NEG_SLOPE * x; }

__device__ __forceinline__ float sel4(const float4 v, int h) {
  float r = v.x;
  r = (h == 1) ? v.y : r;
  r = (h == 2) ? v.z : r;
  r = (h == 3) ? v.w : r;
  return r;
}

__device__ __forceinline__ unsigned char f32_to_fp8(float a) {
  int v = __builtin_amdgcn_cvt_pk_fp8_f32(a, 0.f, 0, false);
  return (unsigned char)(v & 0xff);
}

// ---------------- CSR build ----------------

__global__ void k_hist(const int* __restrict__ dst, int* __restrict__ cnt, int E) {
  int i = blockIdx.x * blockDim.x + threadIdx.x;
  if (i < E) atomicAdd(&cnt[dst[i]], 1);
}

__global__ __launch_bounds__(256) void k_offsets(const int* __restrict__ cnt,
                                                 int* __restrict__ row_start,
                                                 int* __restrict__ gcount, int N) {
  __shared__ int s[256];
  __shared__ int base;
  int tid = threadIdx.x;
  int i = blockIdx.x * 256 + tid;
  int c = (i < N) ? cnt[i] : 0;
  s[tid] = c;
  __syncthreads();
  for (int off = 1; off < 256; off <<= 1) {
    int v = 0;
    if (tid >= off) v = s[tid - off];
    __syncthreads();
    if (tid >= off) s[tid] += v;
    __syncthreads();
  }
  if (tid == 255) base = atomicAdd(gcount, s[255]);
  __syncthreads();
  if (i < N) row_start[i] = base + s[tid] - c;
}

__global__ void k_scatter(const int* __restrict__ src, const int* __restrict__ dst,
                          const int* __restrict__ row_start, int* __restrict__ fill,
                          int* __restrict__ srcs, int E) {
  int i = blockIdx.x * blockDim.x + threadIdx.x;
  if (i < E) {
    int d = dst[i];
    int p = row_start[d] + atomicAdd(&fill[d], 1);
    srcs[p] = src[i];
  }
}

// ---------------- fused prep: wlr0/1/2 + Wt0/1/2 ----------------
// wlr[k*8+h]   = sum_d Ws[k,h*Dh+d]*al[h,d];  wlr[k*8+4+h] = sum_d Wd[k,h*Dh+d]*ar[h,d]
__device__ __forceinline__ void wlr_one(const float* Ws, const float* Wd,
                                        const float* al, const float* ar,
                                        float* wlr, int K, int Dh, int i) {
  int M = 4 * Dh;
  int k = i >> 2, h = i & 3;
  float sl = 0.f, sr = 0.f;
  for (int d = 0; d < Dh; d++) {
    sl += Ws[(size_t)k * M + h * Dh + d] * al[h * Dh + d];
    sr += Wd[(size_t)k * M + h * Dh + d] * ar[h * Dh + d];
  }
  wlr[k * 8 + h] = sl;
  wlr[k * 8 + 4 + h] = sr;
}

__global__ __launch_bounds__(256) void k_prep(
    const float* __restrict__ W0s, const float* __restrict__ W0d,
    const float* __restrict__ a0l, const float* __restrict__ a0r,
    const float* __restrict__ W1s, const float* __restrict__ W1d,
    const float* __restrict__ a1l, const float* __restrict__ a1r,
    const float* __restrict__ W2s, const float* __restrict__ W2d,
    const float* __restrict__ a2l, const float* __restrict__ a2r,
    float* __restrict__ wlr0, float* __restrict__ wlr1, float* __restrict__ wlr2,
    _Float16* __restrict__ Wt0, _Float16* __restrict__ Wt1, _Float16* __restrict__ Wt2) {
  int i = blockIdx.x * 256 + threadIdx.x;
  if (i < 1024) {
    wlr_one(W0s, W0d, a0l, a0r, wlr0, 256, 32, i);
  } else if (i < 1536) {
    wlr_one(W1s, W1d, a1l, a1r, wlr1, 128, 32, i - 1024);
  } else if (i < 2048) {
    wlr_one(W2s, W2d, a2l, a2r, wlr2, 128, 47, i - 1536);
  } else if (i < 2048 + 32768) {
    int j = i - 2048;                 // Wt0[128][256]
    int m = j >> 8, k = j & 255;
    Wt0[j] = (_Float16)W0s[(size_t)k * 128 + m];
  } else if (i < 2048 + 32768 + 16384) {
    int j = i - (2048 + 32768);       // Wt1[128][128]
    int m = j >> 7, k = j & 127;
    Wt1[j] = (_Float16)W1s[(size_t)k * 128 + m];
  } else if (i < 2048 + 32768 + 16384 + 24576) {
    int j = i - (2048 + 32768 + 16384);  // Wt2[192][128], head-padded rows 48*h+c
    int r = j >> 7, k = j & 127;
    int h = r / 48, c = r % 48;
    float v = (c < 47) ? W2s[(size_t)k * 188 + 47 * h + c] : 0.f;
    Wt2[j] = (_Float16)v;
  }
}

// ---------------- MFMA fp16 GEMM + fused el/er; C stored fp8 ----------------
// Block: 64 rows x BN cols, 256 threads (4 waves). el/er partials computed during
// A staging (each A element staged exactly once), reduced via LDS at the end.
template <int BN, typename AT>
__global__ __launch_bounds__(256) void k_gemm_mfma(const AT* __restrict__ A,
                                                   const _Float16* __restrict__ Bt,
                                                   const float* __restrict__ wlr,
                                                   unsigned char* __restrict__ C,
                                                   float* __restrict__ el,
                                                   float* __restrict__ er, int N, int K) {
  constexpr int NT = BN / 64;                 // n-tiles per wave (2 or 3)
  constexpr int ASZ = 4 * 64 * 8;             // 2048 fp16
  constexpr int BSZ = (BN / 16) * 64 * 8;     // 4096 or 6144 fp16
  constexpr int SSZ = ASZ + BSZ;              // >= 64*BN bytes needed for fp8 retile
  __shared__ __align__(16) _Float16 smem[SSZ];
  __shared__ float swlr[2048];                // K*8 <= 2048; reused for eler reduction
  _Float16* As = smem;
  _Float16* Bs = smem + ASZ;

  const int tid = threadIdx.x;
  const int lane = tid & 63;
  const int w = tid >> 6;
  const int row0 = blockIdx.x * 64;

  for (int i = tid; i < K * 8; i += 256) swlr[i] = wlr[i];
  __syncthreads();

  float4v acc[4][NT];
#pragma unroll
  for (int i = 0; i < 4; i++)
#pragma unroll
    for (int j = 0; j < NT; j++) acc[i][j] = (float4v){0.f, 0.f, 0.f, 0.f};
  float p[8] = {0, 0, 0, 0, 0, 0, 0, 0};  // el/er partials (8 = 4 heads el + 4 er)

  const int ar_ = tid >> 2, aq = tid & 3;  // A staging: row ar_, k-quarter aq
  for (int k0 = 0; k0 < K; k0 += 32) {
    {
      int gr = row0 + ar_;
      float a8[8];
      if (gr < N) {
        if constexpr (sizeof(AT) == 4) {
          const float4* pp = (const float4*)&A[(size_t)gr * K + k0 + aq * 8];
          float4 u0 = pp[0], u1 = pp[1];
          a8[0] = u0.x; a8[1] = u0.y; a8[2] = u0.z; a8[3] = u0.w;
          a8[4] = u1.x; a8[5] = u1.y; a8[6] = u1.z; a8[7] = u1.w;
        } else {
          half8 hv = *(const half8*)&A[(size_t)gr * K + k0 + aq * 8];
#pragma unroll
          for (int j = 0; j < 8; j++) a8[j] = (float)hv[j];
        }
      } else {
#pragma unroll
        for (int j = 0; j < 8; j++) a8[j] = 0.f;
      }
      half8 v;
#pragma unroll
      for (int j = 0; j < 8; j++) v[j] = (_Float16)a8[j];
      *(half8*)&As[(size_t)(((ar_ >> 4) * 64) + (ar_ & 15) + 16 * aq) * 8] = v;
      // fused el/er partial
#pragma unroll
      for (int j = 0; j < 8; j++) {
        const float av = a8[j];
        const float* wp = &swlr[(k0 + aq * 8 + j) * 8];
        float4 w0 = *(const float4*)wp;
        float4 w1 = *(const float4*)(wp + 4);
        p[0] += av * w0.x; p[1] += av * w0.y; p[2] += av * w0.z; p[3] += av * w0.w;
        p[4] += av * w1.x; p[5] += av * w1.y; p[6] += av * w1.z; p[7] += av * w1.w;
      }
    }
#pragma unroll
    for (int i = 0; i < NT; i++) {
      int idx = tid + i * 256;
      int n = idx >> 2, q = idx & 3;
      half8 v = *(const half8*)&Bt[(size_t)n * K + k0 + q * 8];
      *(half8*)&Bs[(size_t)((n >> 4) * 64 + (n & 15) + 16 * q) * 8] = v;
    }
    __syncthreads();
    half8 af[4];
#pragma unroll
    for (int mt = 0; mt < 4; mt++) af[mt] = *(half8*)&As[(size_t)(mt * 64 + lane) * 8];
#pragma unroll
    for (int nt = 0; nt < NT; nt++) {
      half8 bf = *(half8*)&Bs[(size_t)((w * NT + nt) * 64 + lane) * 8];
#pragma unroll
      for (int mt = 0; mt < 4; mt++)
        acc[mt][nt] = __builtin_amdgcn_mfma_f32_16x16x32_f16(af[mt], bf, acc[mt][nt], 0, 0, 0);
    }
    __syncthreads();
  }

  // stash eler partials (wlr region no longer needed)
#pragma unroll
  for (int j = 0; j < 8; j++) swlr[(ar_ * 4 + aq) * 8 + j] = p[j];

  // epilogue: C/D layout col=lane&15, row=quad*4+reg -> fp8 bytes into LDS
  unsigned char* cs = (unsigned char*)smem;
  const int quad = lane >> 4;
#pragma unroll
  for (int mt = 0; mt < 4; mt++)
#pragma unroll
    for (int nt = 0; nt < NT; nt++)
#pragma unroll
      for (int reg = 0; reg < 4; reg++) {
        int r = mt * 16 + quad * 4 + reg;
        int cc = (w * NT + nt) * 16 + (lane & 15);
        cs[r * BN + cc] = f32_to_fp8(acc[mt][nt][reg]);
      }
  __syncthreads();
  // el/er reduce + store
  if (tid < 64) {
    int gr = row0 + tid;
    if (gr < N) {
      float e[8];
#pragma unroll
      for (int j = 0; j < 8; j++)
        e[j] = swlr[(tid * 4 + 0) * 8 + j] + swlr[(tid * 4 + 1) * 8 + j] +
               swlr[(tid * 4 + 2) * 8 + j] + swlr[(tid * 4 + 3) * 8 + j];
      *(float4*)&el[(size_t)gr * 4] = make_float4(e[0], e[1], e[2], e[3]);
      *(float4*)&er[(size_t)gr * 4] = make_float4(e[4], e[5], e[6], e[7]);
    }
  }
  // coalesced fp8 C store
  constexpr int PER = (64 * BN) / (256 * 16);
  const uint4* s4 = (const uint4*)cs;
#pragma unroll
  for (int i = 0; i < PER; i++) {
    int idx = tid + i * 256;
    int r = idx / (BN / 16), c16 = idx % (BN / 16);
    int gr = row0 + r;
    if (gr < N) *(uint4*)&C[(size_t)gr * BN + c16 * 16] = s4[idx];
  }
}

// ---------------- edge aggregation, layers 0/1 (F fp8, stride 128) ----------------
// Quarter-wave: 4 groups of 16 lanes, one edge each; lane owns 8 features (8B fp8 load).
__global__ __launch_bounds__(256) void k_edge_mid(
    const unsigned char* __restrict__ F, const float* __restrict__ el,
    const float* __restrict__ er, const int* __restrict__ row_start,
    const int* __restrict__ cnt, const int* __restrict__ srcs,
    const float* __restrict__ bias, _Float16* __restrict__ hout, int N) {
  __shared__ float sEz[4][64][4];
  __shared__ int sU[4][64];
  int lane = threadIdx.x & 63;
  int w = threadIdx.x >> 6;
  int v = blockIdx.x * 4 + w;
  if (v >= N) return;
  int start = row_start[v], deg = cnt[v];
  float4 erv = *(const float4*)&er[(size_t)v * 4];
  const int g = lane >> 4;   // edge subgroup
  const int fl = lane & 15;  // feature slot (8 feats)
  const int h = fl >> 2;     // head
  float acc[8] = {0, 0, 0, 0, 0, 0, 0, 0};
  float4 lsum = make_float4(0.f, 0.f, 0.f, 0.f);

  for (int c = 0; c < deg; c += 64) {
    int take = min(64, deg - c);
    if (lane < take) {
      int u = srcs[start + c + lane];
      float4 e = *(const float4*)&el[(size_t)u * 4];
      float4 ez;
      ez.x = __expf(lrelu(e.x + erv.x));
      ez.y = __expf(lrelu(e.y + erv.y));
      ez.z = __expf(lrelu(e.z + erv.z));
      ez.w = __expf(lrelu(e.w + erv.w));
      lsum.x += ez.x; lsum.y += ez.y; lsum.z += ez.z; lsum.w += ez.w;
      sU[w][lane] = u;
      *(float4*)&sEz[w][lane][0] = ez;
    }
    // wave-private LDS region: same-wave in-order via lgkmcnt; no barrier.
    for (int kk = g; kk < take; kk += 4) {
      int u = sU[w][kk];
      float ezh = sEz[w][kk][h];
      uint2 d = *(const uint2*)&F[(size_t)u * 128 + 8 * fl];
      float2v c0 = __builtin_amdgcn_cvt_pk_f32_fp8((int)d.x, false);
      float2v c1 = __builtin_amdgcn_cvt_pk_f32_fp8((int)d.x, true);
      float2v c2 = __builtin_amdgcn_cvt_pk_f32_fp8((int)d.y, false);
      float2v c3 = __builtin_amdgcn_cvt_pk_f32_fp8((int)d.y, true);
      acc[0] += ezh * c0.x; acc[1] += ezh * c0.y;
      acc[2] += ezh * c1.x; acc[3] += ezh * c1.y;
      acc[4] += ezh * c2.x; acc[5] += ezh * c2.y;
      acc[6] += ezh * c3.x; acc[7] += ezh * c3.y;
    }
  }
#pragma unroll
  for (int j = 0; j < 8; j++) {
    acc[j] += __shfl_xor(acc[j], 16);
    acc[j] += __shfl_xor(acc[j], 32);
  }
#pragma unroll
  for (int msk = 1; msk < 64; msk <<= 1) {
    lsum.x += __shfl_xor(lsum.x, msk);
    lsum.y += __shfl_xor(lsum.y, msk);
    lsum.z += __shfl_xor(lsum.z, msk);
    lsum.w += __shfl_xor(lsum.w, msk);
  }
  if (g == 0) {
    float inv = (deg > 0) ? 1.f / sel4(lsum, h) : 0.f;
    const float4* bp = (const float4*)&bias[8 * fl];
    float4 b0v = bp[0], b1v = bp[1];
    float bb[8] = {b0v.x, b0v.y, b0v.z, b0v.w, b1v.x, b1v.y, b1v.z, b1v.w};
    half8 o;
#pragma unroll
    for (int j = 0; j < 8; j++) o[j] = (_Float16)fmaxf(fmaf(acc[j], inv, bb[j]), 0.f);
    *(half8*)&hout[(size_t)v * 128 + 8 * fl] = o;
  }
}

// ---------------- edge aggregation, layer 2 (F fp8, head-padded 4x48, stride 192) ----------------
__global__ __launch_bounds__(256) void k_edge_final(
    const unsigned char* __restrict__ F, const float* __restrict__ el,
    const float* __restrict__ er, const int* __restrict__ row_start,
    const int* __restrict__ cnt, const int* __restrict__ srcs,
    const float* __restrict__ b2, float* __restrict__ out, int N) {
  __shared__ float sEz[4][64][4];
  __shared__ int sU[4][64];
  __shared__ float red[4][192];
  int lane = threadIdx.x & 63;
  int w = threadIdx.x >> 6;
  int v = blockIdx.x * 4 + w;
  if (v >= N) return;
  int start = row_start[v], deg = cnt[v];
  float4 erv = *(const float4*)&er[(size_t)v * 4];
  const int sub = lane >> 5;   // edge parity
  const int l24 = lane & 31;
  const bool act = l24 < 24;
  const int h = l24 / 6;
  const int j6 = l24 % 6;
  const int foff = 48 * h + 8 * j6;
  float acc[8] = {0, 0, 0, 0, 0, 0, 0, 0};
  float4 lsum = make_float4(0.f, 0.f, 0.f, 0.f);

  for (int c = 0; c < deg; c += 64) {
    int take = min(64, deg - c);
    if (lane < take) {
      int u = srcs[start + c + lane];
      float4 e = *(const float4*)&el[(size_t)u * 4];
      float4 ez;
      ez.x = __expf(lrelu(e.x + erv.x));
      ez.y = __expf(lrelu(e.y + erv.y));
      ez.z = __expf(lrelu(e.z + erv.z));
      ez.w = __expf(lrelu(e.w + erv.w));
      lsum.x += ez.x; lsum.y += ez.y; lsum.z += ez.z; lsum.w += ez.w;
      sU[w][lane] = u;
      *(float4*)&sEz[w][lane][0] = ez;
    }
    if (act) {
      for (int kk = sub; kk < take; kk += 2) {
        int u = sU[w][kk];
        float ezh = sEz[w][kk][h];
        uint2 d = *(const uint2*)&F[(size_t)u * 192 + foff];
        float2v c0 = __builtin_amdgcn_cvt_pk_f32_fp8((int)d.x, false);
        float2v c1 = __builtin_amdgcn_cvt_pk_f32_fp8((int)d.x, true);
        float2v c2 = __builtin_amdgcn_cvt_pk_f32_fp8((int)d.y, false);
        float2v c3 = __builtin_amdgcn_cvt_pk_f32_fp8((int)d.y, true);
        acc[0] += ezh * c0.x; acc[1] += ezh * c0.y;
        acc[2] += ezh * c1.x; acc[3] += ezh * c1.y;
        acc[4] += ezh * c2.x; acc[5] += ezh * c2.y;
        acc[6] += ezh * c3.x; acc[7] += ezh * c3.y;
      }
    }
  }
#pragma unroll
  for (int j = 0; j < 8; j++) acc[j] += __shfl_xor(acc[j], 32);
#pragma unroll
  for (int msk = 1; msk < 64; msk <<= 1) {
    lsum.x += __shfl_xor(lsum.x, msk);
    lsum.y += __shfl_xor(lsum.y, msk);
    lsum.z += __shfl_xor(lsum.z, msk);
    lsum.w += __shfl_xor(lsum.w, msk);
  }
  if (act && sub == 0) {
    float inv = (deg > 0) ? 1.f / sel4(lsum, h) : 0.f;
#pragma unroll
    for (int j = 0; j < 8; j++) {
      int cc = 8 * j6 + j;
      float bv = (cc < 47) ? b2[47 * h + cc] : 0.f;
      red[w][foff + j] = fmaf(acc[j], inv, bv);
    }
  }
  __syncthreads();
  float g = -INFINITY;
  if (lane < 47)
    g = 0.25f * (red[w][lane] + red[w][lane + 48] + red[w][lane + 96] + red[w][lane + 144]);
  float gm = g;
#pragma unroll
  for (int msk = 1; msk < 64; msk <<= 1) gm = fmaxf(gm, __shfl_xor(gm, msk));
  float ex = (lane < 47) ? __expf(g - gm) : 0.f;
  float s = ex;
#pragma unroll
  for (int msk = 1; msk < 64; msk <<= 1) s += __shfl_xor(s, msk);
  if (lane < 47) out[(size_t)v * 47 + lane] = g - gm - __logf(s);
}

// ---------------- launch ----------------
extern "C" void kernel_launch(void* const* d_in, const int* in_sizes, int n_in,
                              void* d_out, int out_size, void* d_ws, size_t ws_size,
                              hipStream_t stream) {
  const float* x = (const float*)d_in[0];
  const int* src = (const int*)d_in[1];
  const int* dst = (const int*)d_in[2];
  const float* W0s = (const float*)d_in[3];
  const float* W0d = (const float*)d_in[4];
  const float* a0l = (const float*)d_in[5];
  const float* a0r = (const float*)d_in[6];
  const float* b0 = (const float*)d_in[7];
  const float* W1s = (const float*)d_in[8];
  const float* W1d = (const float*)d_in[9];
  const float* a1l = (const float*)d_in[10];
  const float* a1r = (const float*)d_in[11];
  const float* b1 = (const float*)d_in[12];
  const float* W2s = (const float*)d_in[13];
  const float* W2d = (const float*)d_in[14];
  const float* a2l = (const float*)d_in[15];
  const float* a2r = (const float*)d_in[16];
  const float* b2 = (const float*)d_in[17];
  float* out = (float*)d_out;

  const int N = in_sizes[0] / 256;  // 100000
  const int E = in_sizes[1];        // 1600000

  char* w = (char*)d_ws;
  size_t off = 0;
  auto alloc = [&](size_t bytes) -> void* {
    void* p = w + off;
    off += (bytes + 255) & ~(size_t)255;
    return p;
  };
  int* gcount = (int*)alloc(4);
  int* cnt = (int*)alloc((size_t)N * 4);
  int* fill = (int*)alloc((size_t)N * 4);
  size_t zbytes = off;  // zero gcount+cnt+fill
  int* row_start = (int*)alloc((size_t)N * 4);
  int* srcs = (int*)alloc((size_t)E * 4);
  float* wlr0 = (float*)alloc(256 * 8 * 4);
  float* wlr1 = (float*)alloc(128 * 8 * 4);
  float* wlr2 = (float*)alloc(128 * 8 * 4);
  _Float16* Wt0 = (_Float16*)alloc(128 * 256 * 2);
  _Float16* Wt1 = (_Float16*)alloc(128 * 128 * 2);
  _Float16* Wt2 = (_Float16*)alloc(192 * 128 * 2);
  float* el = (float*)alloc((size_t)N * 4 * 4);
  float* er = (float*)alloc((size_t)N * 4 * 4);
  unsigned char* F = (unsigned char*)alloc((size_t)N * 192);
  _Float16* Ha = (_Float16*)alloc((size_t)N * 128 * 2);
  _Float16* Hc = (_Float16*)alloc((size_t)N * 128 * 2);
  (void)ws_size;

  hipMemsetAsync(d_ws, 0, zbytes, stream);
  k_hist<<<(E + 255) / 256, 256, 0, stream>>>(dst, cnt, E);
  k_offsets<<<(N + 255) / 256, 256, 0, stream>>>(cnt, row_start, gcount, N);
  k_scatter<<<(E + 255) / 256, 256, 0, stream>>>(src, dst, row_start, fill, srcs, E);
  k_prep<<<(75776 + 255) / 256, 256, 0, stream>>>(W0s, W0d, a0l, a0r, W1s, W1d, a1l, a1r,
                                                  W2s, W2d, a2l, a2r, wlr0, wlr1, wlr2,
                                                  Wt0, Wt1, Wt2);

  int gemm_grid = (N + 63) / 64;
  int node_grid = (N + 3) / 4;

  // layer 0: K=256, fp32 A (x)
  k_gemm_mfma<128, float><<<gemm_grid, 256, 0, stream>>>(x, Wt0, wlr0, F, el, er, N, 256);
  k_edge_mid<<<node_grid, 256, 0, stream>>>(F, el, er, row_start, cnt, srcs, b0, Ha, N);

  // layer 1: K=128, fp16 A
  k_gemm_mfma<128, _Float16><<<gemm_grid, 256, 0, stream>>>(Ha, Wt1, wlr1, F, el, er, N, 128);
  k_edge_mid<<<node_grid, 256, 0, stream>>>(F, el, er, row_start, cnt, srcs, b1, Hc, N);

  // layer 2: K=128, M=192 head-padded (4 x 48, col 47 of each head zero)
  k_gemm_mfma<192, _Float16><<<gemm_grid, 256, 0, stream>>>(Hc, Wt2, wlr2, F, el, er, N, 128);
  k_edge_final<<<node_grid, 256, 0, stream>>>(F, el, er, row_start, cnt, srcs, b2, out, N);
}